// Round 13
// baseline (730.796 us; speedup 1.0000x reference)
//
#include <hip/hip_runtime.h>
#include <hip/hip_bf16.h>
#include <cstddef>
#include <cstdint>
#include <math.h>

typedef __hip_bfloat16 bf16;
typedef _Float16 f16;
typedef _Float16 f16x8 __attribute__((ext_vector_type(8)));
typedef _Float16 f16x2 __attribute__((ext_vector_type(2)));
typedef float f32x4 __attribute__((ext_vector_type(4)));
#define MFMA16(a,b,c) __builtin_amdgcn_mfma_f32_16x16x32_f16(a,b,c,0,0,0)

#define DEV __device__ __forceinline__
DEV float bff(bf16 x){ return __bfloat162float(x); }
DEV bf16 fbf(float x){ return __float2bfloat16(x); }
DEV float lr01(float x){ return x>0.f? x : 0.1f*x; }
DEV float lr02(float x){ return x>0.f? x : 0.2f*x; }
DEV float frcp(float x){ return __builtin_amdgcn_rcpf(x); }
DEV float sigm(float x){ return frcp(1.f+__expf(-x)); }
DEV float tanhe(float x){ float a=fabsf(x); float e=__expf(-2.f*a); float t=(1.f-e)*frcp(1.f+e); return x<0.f? -t : t; }
DEV void stout(void* out, int isf, size_t i, float v){
  if (isf) ((float*)out)[i] = v; else ((bf16*)out)[i] = fbf(v);
}
// bf16 bits (low 16 of u) -> float, no memory round-trip
DEV float bfu_lo(unsigned u){ return __uint_as_float(u << 16); }
DEV float bfu_hi(unsigned u){ return __uint_as_float(u & 0xffff0000u); }
DEV float ldr(const void* p, size_t i, int isf){
  return isf ? ((const float*)p)[i] : bff(((const bf16*)p)[i]);
}

// problem constants
#define NBATCH 2048
#define TSEQ 16
#define KNB 12
#define NGRP 32768
#define NNODES 425984
#define NBK 24576
#define NTOUT 25

// ---------------- dtype detect ----------------
__global__ __launch_bounds__(256) void detect_k(const uint32_t* __restrict__ x, int* __restrict__ flag) {
  __shared__ int cnt;
  if (threadIdx.x == 0) cnt = 0;
  __syncthreads();
  float v = __uint_as_float(x[threadIdx.x]);
  float a = fabsf(v);
  if (a > 1e-12f && a < 100.f) atomicAdd(&cnt, 1);
  __syncthreads();
  if (threadIdx.x == 0) *flag = (cnt >= 128) ? 1 : 0;
}

#define NCVT 55
struct CvtArgs {
  const void* src[NCVT];
  unsigned off[NCVT];
  unsigned cnt[NCVT];
};

// ---------------- convert (blocks <4096) + weight repack (blocks >=4096) ----------------
__global__ __launch_bounds__(256) void cvtprep_k(CvtArgs a, float* __restrict__ dst,
    const int* __restrict__ flag, unsigned total,
    const void* __restrict__ scW, const void* __restrict__ c31W,
    const void* __restrict__ g1W, const void* __restrict__ g2W,
    const void* __restrict__ encWhh, const void* __restrict__ taWhh,
    const void* __restrict__ decWhh,
    f16* __restrict__ wp1t, f16* __restrict__ wp2t,
    float* __restrict__ w1t, float* __restrict__ w2t,
    f16* __restrict__ wench, f16* __restrict__ wtah, f16* __restrict__ wdech) {
  const int isf = *flag;
  if (blockIdx.x < 4096) {
    for (size_t e = (size_t)blockIdx.x*256 + threadIdx.x; e < total; e += (size_t)4096*256) {
      int lo = 0, hi = NCVT-1;
      while (lo < hi) { int mid = (lo+hi+1)>>1; if ((size_t)a.off[mid] <= e) lo = mid; else hi = mid-1; }
      unsigned r = (unsigned)(e - a.off[lo]);
      float v = isf ? ((const float*)a.src[lo])[r] : bff(((const bf16*)a.src[lo])[r]);
      dst[e] = v;
    }
    return;
  }
  int idx = (blockIdx.x - 4096)*256 + threadIdx.x;     // 117,760 total
  if (idx < 12288) {
    int o = idx & 63; int k = idx >> 6; int kh = k >> 6; int i = k & 63;
    wp1t[idx] = (f16)ldr(scW, ((size_t)(o*64+i)*3 + kh)*3, isf);
  } else if (idx < 15360) {
    int e = idx - 12288;
    int o = e & 15; int k = e >> 4; int kh = k >> 6; int i = k & 63;
    wp2t[e] = (f16)ldr(c31W, (size_t)(o*64+i)*3 + kh, isf);
  } else if (idx < 17408) {
    int e = idx - 15360; int k = e >> 6, f = e & 63;
    w1t[e] = ldr(g1W, f*32 + k, isf);
  } else if (idx < 19456) {
    int e = idx - 17408; int k = e >> 5, f = e & 31;
    w2t[e] = ldr(g2W, f*64 + k, isf);
  } else if (idx < 35840) {
    int e = idx - 19456;
    wench[e] = (f16)ldr(encWhh, e, isf);
  } else if (idx < 52224) {
    int e = idx - 35840;
    wtah[e] = (f16)ldr(taWhh, e, isf);
  } else if (idx < 117760) {
    int e = idx - 52224;
    wdech[e] = (f16)ldr(decWhh, e, isf);
  }
}

// ---------------- GAT layer 1: ip_emb + dense(32->64) + esed fused ----------------
__global__ __launch_bounds__(256) void gat_dense1_k(const float* __restrict__ x,
    const float* __restrict__ ipW, const float* __restrict__ ipb,
    const float* __restrict__ Wt, const float* __restrict__ as_, const float* __restrict__ ad_,
    bf16* __restrict__ out, float* __restrict__ esed) {
  __shared__ float As[64][33];
  __shared__ float Ws[32][64];
  __shared__ float xs[64][4];
  __shared__ float wipw[128];
  __shared__ float wipb[32];
  const int tid = threadIdx.x;
  const size_t bm = (size_t)blockIdx.x * 64;
  ((float*)xs)[tid] = x[bm*4 + tid];
  if (tid < 128) wipw[tid] = ipW[tid];
  else if (tid < 160) wipb[tid-128] = ipb[tid-128];
  #pragma unroll
  for (int i = 0; i < 8; i++) ((float*)Ws)[tid + 256*i] = Wt[tid + 256*i];
  __syncthreads();
  #pragma unroll
  for (int i = 0; i < 8; i++) {
    int e = tid + 256*i; int v = e >> 5, f = e & 31;
    float a = wipb[f];
    #pragma unroll
    for (int k = 0; k < 4; k++) a += xs[v][k]*wipw[f*4+k];
    As[v][f] = lr01(a);
  }
  __syncthreads();
  const int v = tid >> 2, f0 = (tid & 3) * 16;
  float acc[16];
  #pragma unroll
  for (int i = 0; i < 16; i++) acc[i] = 0.f;
  #pragma unroll 8
  for (int k = 0; k < 32; k++) {
    float a = As[v][k];
    const float4* wr = (const float4*)&Ws[k][f0];
    #pragma unroll
    for (int q = 0; q < 4; q++) {
      float4 w4 = wr[q];
      acc[4*q+0] += a*w4.x; acc[4*q+1] += a*w4.y; acc[4*q+2] += a*w4.z; acc[4*q+3] += a*w4.w;
    }
  }
  bf16* op = out + (bm+v)*64 + f0;
  #pragma unroll
  for (int i = 0; i < 16; i++) op[i] = fbf(acc[i]);
  float es = 0.f, ed = 0.f;
  #pragma unroll
  for (int i = 0; i < 16; i++) { es += acc[i]*as_[f0+i]; ed += acc[i]*ad_[f0+i]; }
  es += __shfl_xor(es, 1); es += __shfl_xor(es, 2);
  ed += __shfl_xor(ed, 1); ed += __shfl_xor(ed, 2);
  if ((tid & 3) == 0) { esed[(bm+v)*2] = es; esed[(bm+v)*2+1] = ed; }
}

// ---------------- GAT layer 2: dense(64->32) + esed fused ----------------
__global__ __launch_bounds__(256) void gat_dense2_k(const bf16* __restrict__ in,
    const float* __restrict__ Wt, const float* __restrict__ as_, const float* __restrict__ ad_,
    bf16* __restrict__ out, float* __restrict__ esed) {
  __shared__ float As[64][65];
  __shared__ float Ws[64][32];
  const int tid = threadIdx.x;
  const size_t bm = (size_t)blockIdx.x * 64;
  #pragma unroll
  for (int i = 0; i < 16; i++) {
    int lin = tid + 256*i;
    As[lin>>6][lin&63] = bff(in[bm*64 + lin]);
    if (i < 8) ((float*)Ws)[tid + 256*i] = Wt[tid + 256*i];
  }
  __syncthreads();
  const int v = tid >> 2, f0 = (tid & 3) * 8;
  float acc[8];
  #pragma unroll
  for (int i = 0; i < 8; i++) acc[i] = 0.f;
  #pragma unroll 8
  for (int k = 0; k < 64; k++) {
    float a = As[v][k];
    const float4* wr = (const float4*)&Ws[k][f0];
    #pragma unroll
    for (int q = 0; q < 2; q++) {
      float4 w4 = wr[q];
      acc[4*q+0] += a*w4.x; acc[4*q+1] += a*w4.y; acc[4*q+2] += a*w4.z; acc[4*q+3] += a*w4.w;
    }
  }
  bf16* op = out + (bm+v)*32 + f0;
  #pragma unroll
  for (int i = 0; i < 8; i++) op[i] = fbf(acc[i]);
  float es = 0.f, ed = 0.f;
  #pragma unroll
  for (int i = 0; i < 8; i++) { es += acc[i]*as_[f0+i]; ed += acc[i]*ad_[f0+i]; }
  es += __shfl_xor(es, 1); es += __shfl_xor(es, 2);
  ed += __shfl_xor(ed, 1); ed += __shfl_xor(ed, 2);
  if ((tid & 3) == 0) { esed[(bm+v)*2] = es; esed[(bm+v)*2+1] = ed; }
}

__global__ __launch_bounds__(256) void alpha_k(const float* __restrict__ esed, float* __restrict__ alph) {
  int g = blockIdx.x*256 + threadIdx.x;                // NGRP
  size_t base = (size_t)g*13;
  float esv[13], edv[13];
  #pragma unroll
  for (int i = 0; i < 13; i++) { esv[i] = esed[(base+i)*2]; edv[i] = esed[(base+i)*2+1]; }
  float* o = alph + (size_t)g*40;
  float e[13]; float m = -1e30f;
  #pragma unroll
  for (int i = 0; i < 13; i++) { float z = lr02(esv[i] + edv[0]); e[i] = z; m = fmaxf(m, z); }
  float den = 0.f;
  #pragma unroll
  for (int i = 0; i < 13; i++) { e[i] = __expf(e[i]-m); den += e[i]; }
  float inv = 1.f/den;
  #pragma unroll
  for (int i = 0; i < 13; i++) o[i] = e[i]*inv;
  #pragma unroll
  for (int j = 1; j <= 12; j++) {
    float z0 = lr02(esv[0] + edv[j]);
    float z1 = lr02(esv[j] + edv[j]);
    float mm = fmaxf(z0, z1);
    float a0 = __expf(z0-mm), a1 = __expf(z1-mm);
    float s = 1.f/(a0+a1);
    o[13 + 2*(j-1)] = a0*s;
    o[14 + 2*(j-1)] = a1*s;
  }
}

// ---------------- GAT aggregate, vectorized 8 f per thread (16B loads) ----------------
template<int F>
__global__ __launch_bounds__(256) void agg8_k(const bf16* __restrict__ xw, const float* __restrict__ alph,
                                              const float* __restrict__ bias, bf16* __restrict__ out) {
  const int NV = F/8;
  size_t idx = (size_t)blockIdx.x*256 + threadIdx.x;   // NNODES * F/8
  int f8 = (int)(idx % NV);
  size_t vn = idx / NV;
  int node = (int)(vn % 13);
  size_t g = vn / 13;
  size_t base = g*13;
  const float* al = alph + g*40;
  const int f0 = f8*8;
  float acc[8];
  if (node == 0) {
    #pragma unroll
    for (int j = 0; j < 8; j++) acc[j] = 0.f;
    #pragma unroll
    for (int i = 0; i < 13; i++) {
      const uint4 rv = *(const uint4*)&xw[(base+i)*F + f0];
      float a = al[i];
      acc[0] += a*bfu_lo(rv.x); acc[1] += a*bfu_hi(rv.x);
      acc[2] += a*bfu_lo(rv.y); acc[3] += a*bfu_hi(rv.y);
      acc[4] += a*bfu_lo(rv.z); acc[5] += a*bfu_hi(rv.z);
      acc[6] += a*bfu_lo(rv.w); acc[7] += a*bfu_hi(rv.w);
    }
  } else {
    float a0 = al[13 + 2*(node-1)], a1 = al[14 + 2*(node-1)];
    const uint4 r0v = *(const uint4*)&xw[base*F + f0];
    const uint4 r1v = *(const uint4*)&xw[(base+node)*F + f0];
    acc[0] = a0*bfu_lo(r0v.x) + a1*bfu_lo(r1v.x);
    acc[1] = a0*bfu_hi(r0v.x) + a1*bfu_hi(r1v.x);
    acc[2] = a0*bfu_lo(r0v.y) + a1*bfu_lo(r1v.y);
    acc[3] = a0*bfu_hi(r0v.y) + a1*bfu_hi(r1v.y);
    acc[4] = a0*bfu_lo(r0v.z) + a1*bfu_lo(r1v.z);
    acc[5] = a0*bfu_hi(r0v.z) + a1*bfu_hi(r1v.z);
    acc[6] = a0*bfu_lo(r0v.w) + a1*bfu_lo(r1v.w);
    acc[7] = a0*bfu_hi(r0v.w) + a1*bfu_hi(r1v.w);
  }
  bf16* op = out + vn*F + f0;
  #pragma unroll
  for (int j = 0; j < 8; j++) op[j] = fbf(lr01(acc[j] + bias[f0+j]));
}

// ---------------- fused embed + MFMA GEMM (ta branch): C[m][n] = x_row(m)@W[n][:], K=144 pad 160 ----------------
template<bool NBR>
__global__ __launch_bounds__(256) void gemm_embed_mfma_k(
    const float* __restrict__ p_in, const float* __restrict__ v_in,
    const float* __restrict__ di_in, const float* __restrict__ l_in,
    const bf16* __restrict__ h2,
    const float* __restrict__ posW, const float* __restrict__ posb,
    const float* __restrict__ vaW, const float* __restrict__ vab,
    const float* __restrict__ disW, const float* __restrict__ disb,
    const float* __restrict__ laneW, const float* __restrict__ laneb,
    const float* __restrict__ W, f16* __restrict__ C, int t0) {
  __shared__ __align__(16) f16 As[128][40];
  __shared__ __align__(16) f16 Bs[128][40];
  const int tid = threadIdx.x;
  const int bm = blockIdx.x * 128, bn = blockIdx.y * 128;
  const int bz = blockIdx.z;
  const int mm = tid & 127, par = tid >> 7;
  int t, n2;
  if (NBR) { t = t0 + bz; n2 = bm + mm; }
  else { int gm = bm + mm; t = gm >> 11; n2 = gm & 2047; }
  const int NROW = NBR ? NBK : NBATCH;
  size_t rn = (size_t)t*NROW + n2;
  const float px0 = p_in[rn*2], px1 = p_in[rn*2+1];
  const float vx0 = v_in[rn*2], vx1 = v_in[rn*2+1];
  const float dx  = di_in[rn];
  const float lx0 = l_in[rn*2], lx1 = l_in[rn*2+1];
  const int b = NBR ? (n2 / KNB) : n2;
  const int node_off = NBR ? (1 + n2 % KNB) : 0;
  const bf16* h2p = h2 + (((size_t)t*NBATCH + b)*13 + node_off)*32;
  const int wn = bn + mm;
  const int l = tid & 63, wv = tid >> 6;
  const int lr = l & 15, lq = l >> 4;
  f32x4 acc[2][8];
  #pragma unroll
  for (int rt = 0; rt < 2; rt++)
    #pragma unroll
    for (int ct = 0; ct < 8; ct++) acc[rt][ct] = (f32x4){0.f,0.f,0.f,0.f};
  for (int ks = 0; ks < 5; ks++) {
    const int k0 = ks*32;
    #pragma unroll
    for (int e = 0; e < 16; e++) {
      int kk = par + 2*e;
      int f = k0 + kk;
      float val;
      if (f < 32) {
        val = lr01(px0*posW[f*2] + px1*posW[f*2+1] + posb[f]);
      } else if (f < 64) {
        int ff = f-32;
        val = lr01(vx0*vaW[ff*2] + vx1*vaW[ff*2+1] + vab[ff]);
      } else if (f < 80) {
        int ff = f-64;
        val = lr01(dx*disW[ff] + disb[ff]);
      } else if (f < 112) {
        int ff = f-80;
        val = lr01(lx0*laneW[ff*2] + lx1*laneW[ff*2+1] + laneb[ff]);
      } else if (f < 144) {
        val = bff(h2p[f-112]);
      } else val = 0.f;
      As[mm][kk] = (f16)val;
      Bs[mm][kk] = (f < 144) ? (f16)W[(size_t)wn*144 + f] : (f16)0.f;
    }
    __syncthreads();
    f16x8 a0 = *(const f16x8*)&As[wv*32 + lr][lq*8];
    f16x8 a1 = *(const f16x8*)&As[wv*32 + 16 + lr][lq*8];
    #pragma unroll
    for (int ct = 0; ct < 8; ct++) {
      f16x8 bfr = *(const f16x8*)&Bs[ct*16 + lr][lq*8];
      acc[0][ct] = MFMA16(a0, bfr, acc[0][ct]);
      acc[1][ct] = MFMA16(a1, bfr, acc[1][ct]);
    }
    __syncthreads();
  }
  #pragma unroll
  for (int rt = 0; rt < 2; rt++)
    #pragma unroll
    for (int ct = 0; ct < 8; ct++)
      #pragma unroll
      for (int rg = 0; rg < 4; rg++) {
        int row = wv*32 + rt*16 + lq*4 + rg;
        int col = ct*16 + lr;
        size_t orow = NBR ? ((size_t)bz*NBK + bm + row) : (size_t)(bm + row);
        C[orow*256 + bn + col] = (f16)acc[rt][ct][rg];
      }
}

// ---------------- combined enc(v8 gate-split) + ta-lstm64 mega kernel ----------------
__global__ __launch_bounds__(512, 4) void enc_ta_mega_k(
    const float* __restrict__ p_in, const float* __restrict__ v_in,
    const float* __restrict__ di_in, const float* __restrict__ l_in,
    const bf16* __restrict__ h2,
    const float* __restrict__ posW, const float* __restrict__ posb,
    const float* __restrict__ vaW, const float* __restrict__ vab,
    const float* __restrict__ disW, const float* __restrict__ disb,
    const float* __restrict__ laneW, const float* __restrict__ laneb,
    const float* __restrict__ Wih, const f16* __restrict__ Whh16,
    const float* __restrict__ bih, const float* __restrict__ bhh,
    float* __restrict__ hstate,
    const f16* __restrict__ XWta, const f16* __restrict__ Whh16ta,
    const float* __restrict__ bihta, const float* __restrict__ bhhta,
    float* __restrict__ h_all_ta) {
  __shared__ __align__(16) union SMem {
    struct { f16 As_s[2][16][168]; f16 h_s[2][16][72]; float gates[16][258]; } e;
    struct { f16 h_s[16][72]; float gates[16][260]; } a;
  } sm;
  const int tid = threadIdx.x;
  const int l = tid & 63;
  const int lr = l & 15, lq = l >> 4;

  if (blockIdx.x < 128) {
    // ================= ta lstm64 path (t0=0, TSEQ steps, nrows=NBATCH) =================
    const int r0 = blockIdx.x * 16;
    const int wv = tid >> 6;           // 0..7; waves 0..3 active
    const int u = l, rg = wv;
    f16x8 bf[4][2];
    if (wv < 4) {
      #pragma unroll
      for (int ct = 0; ct < 4; ct++)
        #pragma unroll
        for (int kt = 0; kt < 2; kt++)
          bf[ct][kt] = *(const f16x8*)&Whh16ta[(size_t)(wv*64 + ct*16 + lr)*64 + kt*32 + lq*8];
    }
    float bj4[4];
    #pragma unroll
    for (int g = 0; g < 4; g++) bj4[g] = bihta[g*64+u] + bhhta[g*64+u];
    for (int i = tid; i < 16*64; i += 512) sm.a.h_s[i>>6][i&63] = (f16)0.f;
    float c[4] = {0.f,0.f,0.f,0.f};
    __syncthreads();
    #pragma unroll 1
    for (int s = 0; s < TSEQ; s++) {
      if (wv < 4) {
        f16x8 a0 = *(const f16x8*)&sm.a.h_s[lr][lq*8];
        f16x8 a1 = *(const f16x8*)&sm.a.h_s[lr][32 + lq*8];
        f32x4 acc[4];
        #pragma unroll
        for (int ct = 0; ct < 4; ct++) {
          acc[ct] = (f32x4){0.f,0.f,0.f,0.f};
          acc[ct] = MFMA16(a0, bf[ct][0], acc[ct]);
          acc[ct] = MFMA16(a1, bf[ct][1], acc[ct]);
        }
        #pragma unroll
        for (int ct = 0; ct < 4; ct++)
          #pragma unroll
          for (int q2 = 0; q2 < 4; q2++)
            sm.a.gates[lq*4 + q2][wv*64 + ct*16 + lr] = acc[ct][q2];
      }
      __syncthreads();
      if (wv < 4) {
        const f16* xwrow = XWta + ((size_t)s*NBATCH + r0)*256;
        #pragma unroll
        for (int q = 0; q < 4; q++) {
          const int r = rg*4 + q;
          float gi = sm.a.gates[r][u]     + bj4[0] + (float)xwrow[(size_t)r*256 + u];
          float gf = sm.a.gates[r][64+u]  + bj4[1] + (float)xwrow[(size_t)r*256 + 64 + u];
          float gg = sm.a.gates[r][128+u] + bj4[2] + (float)xwrow[(size_t)r*256 + 128 + u];
          float go = sm.a.gates[r][192+u] + bj4[3] + (float)xwrow[(size_t)r*256 + 192 + u];
          float cv = sigm(gf)*c[q] + sigm(gi)*tanhe(gg);
          c[q] = cv;
          float hv = sigm(go)*tanhe(cv);
          sm.a.h_s[r][u] = (f16)hv;
          h_all_ta[((size_t)s*NBATCH + r0 + r)*64 + u] = hv;
        }
      }
      __syncthreads();
    }
    return;
  }

  // ================= enc path =================
  const int r0 = (blockIdx.x - 128) * 16;
  const int w = tid >> 6;              // 8 waves
  const int cu0 = w*16 + lr;
  const int cu1 = 128 + cu0;
  f16x8 bxw[2][5];
  f16x8 bhw[2][2];
  float bv[2];
  #pragma unroll
  for (int s = 0; s < 2; s++) {
    const int cu = s ? cu1 : cu0;
    const float* wr = Wih + (size_t)cu*144;
    #pragma unroll
    for (int ks = 0; ks < 5; ks++) {
      f16x8 v;
      #pragma unroll
      for (int j = 0; j < 8; j++) {
        int k = ks*32 + lq*8 + j;
        v[j] = (k < 144) ? (f16)wr[k] : (f16)0.f;
      }
      bxw[s][ks] = v;
    }
    #pragma unroll
    for (int kt = 0; kt < 2; kt++)
      bhw[s][kt] = *(const f16x8*)&Whh16[(size_t)cu*64 + kt*32 + lq*8];
    bv[s] = bih[cu] + bhh[cu];
  }
  const int prow = tid & 15;
  const int pq = tid >> 4;
  const int n2 = r0 + prow;
  const int bb = n2 / KNB;
  const int noff = 1 + n2 - bb*KNB;
  float c0 = 0.f, c1 = 0.f;
  float La = 0.f, Lb = 0.f;
  uint4 HA = {0,0,0,0};
  for (int i = tid; i < 16*64; i += 512) sm.e.h_s[0][i>>6][i&63] = (f16)0.f;

#define ENC_ISSUE(TP) do {                                                   \
    const size_t rnp = (size_t)(TP)*NBK + n2;                                \
    if (pq < 4)       { float2 p = *(const float2*)(p_in + rnp*2); La = p.x; Lb = p.y; } \
    else if (pq < 8)  { float2 p = *(const float2*)(v_in + rnp*2); La = p.x; Lb = p.y; } \
    else if (pq < 10) { La = di_in[rnp]; }                                   \
    else if (pq < 14) { float2 p = *(const float2*)(l_in + rnp*2); La = p.x; Lb = p.y; } \
    else if (pq < 18) { HA = *(const uint4*)(h2 + (((size_t)(TP)*NBATCH + bb)*13 + noff)*32 + (pq-14)*8); } \
  } while (0)

#define ENC_STAGE(BUF) do {                                                  \
    if (pq < 20) {                                                           \
      const int f0 = pq*8;                                                   \
      f16x8 v;                                                               \
      if (f0 < 32) {                                                         \
        _Pragma("unroll")                                                    \
        for (int j = 0; j < 8; j++)                                          \
          v[j] = (f16)lr01(La*posW[(f0+j)*2] + Lb*posW[(f0+j)*2+1] + posb[f0+j]); \
      } else if (f0 < 64) {                                                  \
        _Pragma("unroll")                                                    \
        for (int j = 0; j < 8; j++) {                                        \
          int ff = f0+j-32;                                                  \
          v[j] = (f16)lr01(La*vaW[ff*2] + Lb*vaW[ff*2+1] + vab[ff]);         \
        }                                                                    \
      } else if (f0 < 80) {                                                  \
        _Pragma("unroll")                                                    \
        for (int j = 0; j < 8; j++) {                                        \
          int ff = f0+j-64;                                                  \
          v[j] = (f16)lr01(La*disW[ff] + disb[ff]);                          \
        }                                                                    \
      } else if (f0 < 112) {                                                 \
        _Pragma("unroll")                                                    \
        for (int j = 0; j < 8; j++) {                                        \
          int ff = f0+j-80;                                                  \
          v[j] = (f16)lr01(La*laneW[ff*2] + Lb*laneW[ff*2+1] + laneb[ff]);   \
        }                                                                    \
      } else if (f0 < 144) {                                                 \
        v[0] = (f16)bfu_lo(HA.x); v[1] = (f16)bfu_hi(HA.x);                  \
        v[2] = (f16)bfu_lo(HA.y); v[3] = (f16)bfu_hi(HA.y);                  \
        v[4] = (f16)bfu_lo(HA.z); v[5] = (f16)bfu_hi(HA.z);                  \
        v[6] = (f16)bfu_lo(HA.w); v[7] = (f16)bfu_hi(HA.w);                  \
      } else {                                                               \
        _Pragma("unroll")                                                    \
        for (int j = 0; j < 8; j++) v[j] = (f16)0.f;                         \
      }                                                                      \
      *(f16x8*)&sm.e.As_s[BUF][prow][f0] = v;                                \
    }                                                                        \
  } while (0)

  ENC_ISSUE(0);
  ENC_STAGE(0);
  __syncthreads();
  int cur = 0;
  #pragma unroll 1
  for (int t = 0; t < TSEQ; t++) {
    const int tp = (t+1 < TSEQ) ? t+1 : t;
    ENC_ISSUE(tp);
    {
      f16x8 ae0 = *(const f16x8*)&sm.e.As_s[cur][lr][lq*8];
      f16x8 ae1 = *(const f16x8*)&sm.e.As_s[cur][lr][32 + lq*8];
      f16x8 ae2 = *(const f16x8*)&sm.e.As_s[cur][lr][64 + lq*8];
      f16x8 ae3 = *(const f16x8*)&sm.e.As_s[cur][lr][96 + lq*8];
      f16x8 ae4 = *(const f16x8*)&sm.e.As_s[cur][lr][128 + lq*8];
      f16x8 ah0 = *(const f16x8*)&sm.e.h_s[cur][lr][lq*8];
      f16x8 ah1 = *(const f16x8*)&sm.e.h_s[cur][lr][32 + lq*8];
      #pragma unroll
      for (int s = 0; s < 2; s++) {
        f32x4 a = (f32x4){0.f,0.f,0.f,0.f};
        a = MFMA16(ae0, bxw[s][0], a);
        a = MFMA16(ae1, bxw[s][1], a);
        a = MFMA16(ae2, bxw[s][2], a);
        a = MFMA16(ae3, bxw[s][3], a);
        a = MFMA16(ae4, bxw[s][4], a);
        a = MFMA16(ah0, bhw[s][0], a);
        a = MFMA16(ah1, bhw[s][1], a);
        const int cu = s ? cu1 : cu0;
        #pragma unroll
        for (int q = 0; q < 4; q++)
          sm.e.gates[lq*4 + q][cu] = a[q] + bv[s];
      }
    }
    __syncthreads();
    {
      const int u0 = pq*2;
      const float* gr = &sm.e.gates[prow][0];
      float gi0 = gr[u0],       gi1 = gr[u0+1];
      float gf0 = gr[64+u0],    gf1 = gr[64+u0+1];
      float gg0 = gr[128+u0],   gg1 = gr[128+u0+1];
      float go0 = gr[192+u0],   go1 = gr[192+u0+1];
      float cv0 = sigm(gf0)*c0 + sigm(gi0)*tanhe(gg0);
      float cv1 = sigm(gf1)*c1 + sigm(gi1)*tanhe(gg1);
      c0 = cv0; c1 = cv1;
      f16x2 hv;
      hv[0] = (f16)(sigm(go0)*tanhe(cv0));
      hv[1] = (f16)(sigm(go1)*tanhe(cv1));
      *(f16x2*)&sm.e.h_s[cur^1][prow][u0] = hv;
    }
    ENC_STAGE(cur^1);
    __syncthreads();
    cur ^= 1;
  }
#undef ENC_ISSUE
#undef ENC_STAGE
  for (int i = tid; i < 16*64; i += 512)
    hstate[(size_t)(r0 + (i>>6))*64 + (i&63)] = (float)sm.e.h_s[cur][i>>6][i&63];
}

// ---------------- merged heads: gemm_bt (blocks 0..63) + latlon (blocks 64..71) ----------------
__global__ __launch_bounds__(256, 2) void head_k(const bf16* __restrict__ A, const float* __restrict__ W,
    float* __restrict__ C, int N, int Kd,
    const float* __restrict__ e192,
    const float* __restrict__ latW, const float* __restrict__ latb,
    const float* __restrict__ lonW, const float* __restrict__ lonb,
    void* __restrict__ out, const int* __restrict__ flag) {
  const int tid = threadIdx.x;
  if (blockIdx.x < 64) {
    __shared__ __align__(16) float As[8][132];
    __shared__ __align__(16) float Bs[8][132];
    const int bm = (blockIdx.x >> 2) * 128, bn = (blockIdx.x & 3) * 128;
    const int tx = tid & 15, ty = tid >> 4;
    float acc[8][8];
    #pragma unroll
    for (int i = 0; i < 8; i++)
      #pragma unroll
      for (int j = 0; j < 8; j++) acc[i][j] = 0.f;
    for (int k0 = 0; k0 < Kd; k0 += 8) {
      #pragma unroll
      for (int i = 0; i < 4; i++) {
        int lin = tid + 256*i;
        int kk = lin & 7, mm = lin >> 3;
        int gk = k0 + kk;
        As[kk][mm] = (gk < Kd) ? bff(A[(size_t)(bm+mm)*Kd + gk]) : 0.f;
        Bs[kk][mm] = (gk < Kd) ? W[(size_t)(bn+mm)*Kd + gk] : 0.f;
      }
      __syncthreads();
      #pragma unroll
      for (int kk = 0; kk < 8; kk++) {
        float4 a0 = *(const float4*)&As[kk][ty*4];
        float4 a1 = *(const float4*)&As[kk][64+ty*4];
        float4 b0 = *(const float4*)&Bs[kk][tx*4];
        float4 b1 = *(const float4*)&Bs[kk][64+tx*4];
        float av[8] = {a0.x,a0.y,a0.z,a0.w,a1.x,a1.y,a1.z,a1.w};
        float bvv[8] = {b0.x,b0.y,b0.z,b0.w,b1.x,b1.y,b1.z,b1.w};
        #pragma unroll
        for (int i = 0; i < 8; i++)
          #pragma unroll
          for (int j = 0; j < 8; j++) acc[i][j] += av[i]*bvv[j];
      }
      __syncthreads();
    }
    #pragma unroll
    for (int i = 0; i < 8; i++) {
      int m = bm + (i>>2)*64 + ty*4 + (i&3);
      #pragma unroll
      for (int jh = 0; jh < 2; jh++) {
        float4 v = make_float4(acc[i][jh*4+0], acc[i][jh*4+1], acc[i][jh*4+2], acc[i][jh*4+3]);
        *(float4*)&C[(size_t)m*N + bn + jh*64 + tx*4] = v;
      }
    }
  } else {
    int b = (blockIdx.x - 64)*256 + tid;               // NBATCH
    const int isf = *flag;
    const float* e = e192 + (size_t)b*192;
    float s[3];
    #pragma unroll
    for (int c2 = 0; c2 < 3; c2++) {
      float acc = latb[c2];
      for (int k = 0; k < 192; k++) acc += e[k]*latW[c2*192+k];
      s[c2] = acc;
    }
    float m = fmaxf(s[0], fmaxf(s[1], s[2]));
    float e0 = __expf(s[0]-m), e1 = __expf(s[1]-m), e2 = __expf(s[2]-m);
    float inv = 1.f/(e0+e1+e2);
    stout(out, isf, 256000 + (size_t)b*3 + 0, e0*inv);
    stout(out, isf, 256000 + (size_t)b*3 + 1, e1*inv);
    stout(out, isf, 256000 + (size_t)b*3 + 2, e2*inv);
    float q[2];
    #pragma unroll
    for (int c2 = 0; c2 < 2; c2++) {
      float acc = lonb[c2];
      for (int k = 0; k < 192; k++) acc += e[k]*lonW[c2*192+k];
      q[c2] = acc;
    }
    float m2 = fmaxf(q[0], q[1]);
    float f0 = __expf(q[0]-m2), f1 = __expf(q[1]-m2);
    float inv2 = 1.f/(f0+f1);
    stout(out, isf, 262144 + (size_t)b*2 + 0, f0*inv2);
    stout(out, isf, 262144 + (size_t)b*2 + 1, f1*inv2);
  }
}

// ---------------- MFMA LSTM H=128 (dec) + fused output projection ----------------
__global__ __launch_bounds__(512) void lstm128_out_k(const float* __restrict__ XW,
    const f16* __restrict__ Whh16, const float* __restrict__ bih, const float* __restrict__ bhh,
    int steps, const float* __restrict__ opW, const float* __restrict__ opb,
    void* __restrict__ out, const int* __restrict__ flag) {
  __shared__ __align__(16) f16 h_s[2][16][136];
  __shared__ float hsf[2][16][132];
  __shared__ float opWs[640];
  __shared__ float opbs[5];
  const int tid = threadIdx.x;
  const int r0 = blockIdx.x * 16;
  const int l = tid & 63, wv = tid >> 6;
  const int lr = l & 15, lq = l >> 4;
  const int u = wv*16 + lr;
  const int isf = *flag;
  f16x8 bf[4][4];
  #pragma unroll
  for (int g = 0; g < 4; g++)
    #pragma unroll
    for (int kt = 0; kt < 4; kt++)
      bf[g][kt] = *(const f16x8*)&Whh16[(size_t)(g*128 + u)*128 + kt*32 + lq*8];
  float xr[4][4];
  #pragma unroll
  for (int g = 0; g < 4; g++) {
    float bj = bih[g*128 + u] + bhh[g*128 + u];
    #pragma unroll
    for (int rg = 0; rg < 4; rg++)
      xr[g][rg] = XW[(size_t)(r0 + lq*4 + rg)*512 + g*128 + u] + bj;
  }
  for (int i = tid; i < 16*128; i += 512) h_s[0][i>>7][i&127] = (f16)0.f;
  for (int i = tid; i < 640; i += 512) opWs[i] = opW[i];
  if (tid < 5) opbs[tid] = opb[tid];
  float c[4] = {0.f,0.f,0.f,0.f};
  __syncthreads();
  int cur = 0;
  #pragma unroll 1
  for (int t = 0; t < steps; t++) {
    f16x8 a0 = *(const f16x8*)&h_s[cur][lr][lq*8];
    f16x8 a1 = *(const f16x8*)&h_s[cur][lr][32 + lq*8];
    f16x8 a2 = *(const f16x8*)&h_s[cur][lr][64 + lq*8];
    f16x8 a3 = *(const f16x8*)&h_s[cur][lr][96 + lq*8];
    f32x4 acc[4];
    #pragma unroll
    for (int g = 0; g < 4; g++) {
      acc[g] = (f32x4){0.f,0.f,0.f,0.f};
      acc[g] = MFMA16(a0, bf[g][0], acc[g]);
      acc[g] = MFMA16(a1, bf[g][1], acc[g]);
      acc[g] = MFMA16(a2, bf[g][2], acc[g]);
      acc[g] = MFMA16(a3, bf[g][3], acc[g]);
    }
    #pragma unroll
    for (int rg = 0; rg < 4; rg++) {
      const int row = lq*4 + rg;
      float gi = acc[0][rg] + xr[0][rg];
      float gf = acc[1][rg] + xr[1][rg];
      float gg = acc[2][rg] + xr[2][rg];
      float go = acc[3][rg] + xr[3][rg];
      float cv = sigm(gf)*c[rg] + sigm(gi)*tanhe(gg);
      c[rg] = cv;
      float hv = sigm(go)*tanhe(cv);
      h_s[cur^1][row][u] = (f16)hv;
      hsf[cur^1][row][u] = hv;
    }
    __syncthreads();
    if (tid < 80) {
      const int row = tid / 5, c2 = tid - (tid/5)*5;
      float acc2 = opbs[c2];
      const float* hr = &hsf[cur^1][row][0];
      for (int k = 0; k < 128; k++) acc2 += hr[k]*opWs[c2*128+k];
      size_t oidx = ((size_t)t*NBATCH + r0 + row)*5 + c2;
      float v = (c2 < 2) ? acc2 : (c2 < 4 ? __expf(acc2) : tanhe(acc2));
      stout(out, isf, oidx, v);
    }
    cur ^= 1;
  }
}

// ---------------- fused social conv + inline temporal attention ----------------
// conv1 -> conv2 -> [ta scores -> ta ctx] -> pool/e192/encd. The ta phases replicate
// ta_fused_k arithmetic exactly (t-major, h-ascending dots, same softmax chain).
__global__ __launch_bounds__(256) void fused_conv_k(const float* __restrict__ nenc,
    const f16* __restrict__ wp1t, const f16* __restrict__ wp2t,
    const float* __restrict__ scb, const float* __restrict__ c31b,
    const float* __restrict__ hs, const float* __restrict__ taW, const float* __restrict__ tab,
    const float* __restrict__ dynW, const float* __restrict__ dynb,
    const float* __restrict__ lat_enc, const float* __restrict__ lon_enc,
    float* __restrict__ e192, bf16* __restrict__ encd) {
  __shared__ f16 ws1[12288];
  __shared__ f16 ws2[3072];
  __shared__ float img[4][13][64];
  __shared__ float c1s[4][64][12];
  __shared__ float c2s[4][16][9];
  __shared__ float scl[4][16];
  __shared__ float hencl[4][32];
  const int tid = threadIdx.x;
  const int l = tid & 63, wv = tid >> 6;
  const int b = blockIdx.x*4 + wv;
  #pragma unroll
  for (int it = 0; it < 24; it++) ((uint32_t*)ws1)[tid + 256*it] = ((const uint32_t*)wp1t)[tid + 256*it];
  #pragma unroll
  for (int it = 0; it < 6; it++) ((uint32_t*)ws2)[tid + 256*it] = ((const uint32_t*)wp2t)[tid + 256*it];
  #pragma unroll
  for (int it = 0; it < 13; it++)
    img[wv][it][l] = (it < 12) ? nenc[((size_t)b*12 + it)*64 + l] : 0.f;
  __syncthreads();
  {
    const int o = l;
    float acc[11];
    float bv = scb[o];
    #pragma unroll
    for (int h = 0; h < 11; h++) acc[h] = bv;
    for (int k = 0; k < 192; k++) {
      int kh = k >> 6, i = k & 63;
      float w = (float)ws1[k*64 + o];
      const float* ic = img[wv][kh];
      #pragma unroll
      for (int h = 0; h < 11; h++) acc[h] += ic[h*64 + i] * w;
    }
    #pragma unroll
    for (int h = 0; h < 11; h++) c1s[wv][o][h] = lr01(acc[h]);
  }
  __syncthreads();
  if (l < 48) {
    const int o2 = l / 3, jg = l - o2*3;
    float acc[3];
    float bv = c31b[o2];
    #pragma unroll
    for (int m = 0; m < 3; m++) acc[m] = bv;
    for (int k = 0; k < 192; k++) {
      int kh = k >> 6, i = k & 63;
      float w = (float)ws2[k*16 + o2];
      #pragma unroll
      for (int m = 0; m < 3; m++) acc[m] += c1s[wv][i][jg*3 + m + kh] * w;
    }
    #pragma unroll
    for (int m = 0; m < 3; m++) c2s[wv][o2][jg*3 + m] = lr01(acc[m]);
  }
  // ---- ta scores: lane i<16 computes score i for batch b (same order as ta_fused_k) ----
  if (l < 16) {
    const int i = l;
    float acc = tab[i];
    for (int t = 0; t < 16; t++) {
      const float* hr = hs + ((size_t)t*NBATCH + b)*64;
      const float* wr = taW + (size_t)i*1024 + t*64;
      #pragma unroll
      for (int h = 0; h < 64; h++) acc += hr[h]*wr[h];
    }
    scl[wv][i] = fmaxf(acc, 0.f);
  }
  __syncthreads();
  // ---- ta softmax + ctx: lane o<32 ----
  if (l < 32) {
    const int o = l;
    const float* s = scl[wv];
    float m = s[0];
    #pragma unroll
    for (int t = 1; t < 16; t++) m = fmaxf(m, s[t]);
    float e[16]; float den = 0.f;
    #pragma unroll
    for (int t = 0; t < 16; t++) { e[t] = __expf(s[t]-m); den += e[t]; }
    float inv = 1.f/den;
    float acc = dynb[o];
    for (int t = 0; t < 16; t++) {
      const float* hr = hs + ((size_t)t*NBATCH + b)*64;
      float inner = 0.f;
      #pragma unroll
      for (int h = 0; h < 64; h++) inner += hr[h]*dynW[(size_t)o*64 + h];
      acc += (e[t]*inv)*inner;
    }
    hencl[wv][o] = lr01(acc);
  }
  __syncthreads();
  for (int it = 0; it < 4; it++) {
    int k = l + it*64;
    if (k >= 197) break;
    float val;
    if (k < 192) {
      if (k < 160) {
        bool is_av = (k >= 80);
        int rel = is_av ? (k - 80) : k;
        int o = rel / 5, p = rel - o*5;
        const float* r = c2s[wv][o];
        float v2 = r[2*p];
        if (p == 0) val = is_av ? v2*0.5f : v2;
        else { float v1 = r[2*p-1]; val = is_av ? (v1+v2)*0.5f : fmaxf(v1, v2); }
      } else {
        val = hencl[wv][k-160];
      }
      e192[(size_t)b*192 + k] = val;
    } else if (k < 195) {
      val = lat_enc[(size_t)b*3 + (k-192)];
    } else {
      val = lon_enc[(size_t)b*2 + (k-195)];
    }
    encd[(size_t)b*197 + k] = fbf(val);
  }
}

// ---------------- workspace layout (f32-slot offsets) ----------------
static const size_t OFF_H2   = 0;
static const size_t OFF_P    = 6815744;     // h1 (GAT)
static const size_t OFF_Q    = 20447232;    // xw1/xw2 (GAT)
static const size_t OFF_ESED = 34078720;
static const size_t OFF_ALPH = 34930688;    // -> end 36,241,408
static const size_t OFF_XWTA = 6815744;     // f16 (ta phase)
static const size_t OFF_HSTA = 15204352;    // ta phase
static const size_t OFF_HST  = 23691264;
static const size_t OFF_E192 = 28573696;
static const size_t OFF_ENCD = 28966912;
static const size_t OFF_XWD  = 29168640;
static const size_t OFF_CVT  = 36241408;
static const size_t OFF_WP1T = 41280000;
static const size_t OFF_WP2T = 41286144;
static const size_t OFF_W1T  = 41287680;
static const size_t OFF_W2T  = 41289728;
static const size_t OFF_WENC = 41291776;    // f16 x 16384
static const size_t OFF_WTAH = 41299968;    // f16 x 16384
static const size_t OFF_WDECH= 41308160;    // f16 x 65536 (32768 slots)
static const size_t OFF_FLAG = 41400000;

extern "C" void kernel_launch(void* const* d_in, const int* in_sizes, int n_in,
                              void* d_out, int out_size, void* d_ws, size_t ws_size,
                              hipStream_t stream) {
  (void)in_sizes; (void)n_in; (void)out_size; (void)ws_size;
  float* ws = (float*)d_ws;
  int* flag = (int*)(ws + OFF_FLAG);

  static const int   cidx[NCVT] = {0,3,4,5,6,7,8,9,10,12,13,
    14,15,16,17,18,19,20,21,22,23,24,25,26,27,28,29,30,31,
    32,33,34,35,36,37,38,39,40,41,42,43,44,45,46,47,
    48,49,50,51,52,53,54,55,56,57};
  static const unsigned ccnt[NCVT] = {1703936,65536,65536,32768,65536,786432,786432,393216,786432,6144,4096,
    128,32,2048,64,64,64,2048,32,32,32,64,32,64,32,16,16,64,32,
    36864,16384,256,256,36864,16384,256,256,16384,16,2048,32,36864,64,3072,16,
    100864,65536,512,512,640,5,576,3,384,2};
  CvtArgs ca;
  unsigned total = 0;
  float* cp[58];
  for (int i = 0; i < NCVT; i++) {
    ca.src[i] = d_in[cidx[i]];
    ca.off[i] = total;
    ca.cnt[i] = ccnt[i];
    cp[cidx[i]] = ws + OFF_CVT + total;
    total += ccnt[i];
  }
  detect_k<<<1,256,0,stream>>>((const uint32_t*)d_in[0], flag);

  void* out = d_out;
  bf16*  h2    = (bf16*)(ws + OFF_H2);
  bf16*  h1    = (bf16*)(ws + OFF_P);
  bf16*  xw1   = (bf16*)(ws + OFF_Q);
  bf16*  xw2   = (bf16*)(ws + OFF_Q);
  float* esed  = ws + OFF_ESED;
  float* alph  = ws + OFF_ALPH;
  f16*   xwta  = (f16*)(ws + OFF_XWTA);
  float* hsta  = ws + OFF_HSTA;
  float* hst   = ws + OFF_HST;
  float* e192  = ws + OFF_E192;
  bf16*  encd  = (bf16*)(ws + OFF_ENCD);
  float* xwd   = ws + OFF_XWD;
  f16*   wp1t  = (f16*)(ws + OFF_WP1T);
  f16*   wp2t  = (f16*)(ws + OFF_WP2T);
  float* w1t   = ws + OFF_W1T;
  float* w2t   = ws + OFF_W2T;
  f16*   wench = (f16*)(ws + OFF_WENC);
  f16*   wtah  = (f16*)(ws + OFF_WTAH);
  f16*   wdech = (f16*)(ws + OFF_WDECH);

  // ---- convert + weight repack in one kernel ----
  cvtprep_k<<<4556,256,0,stream>>>(ca, ws + OFF_CVT, flag, total,
      d_in[44], d_in[46], d_in[16], d_in[20], d_in[33], d_in[37], d_in[49],
      wp1t, wp2t, w1t, w2t, wench, wtah, wdech);

  // ---- GAT (fused ip_emb+dense1+esed, dense2+esed) ----
  gat_dense1_k<<<6656,256,0,stream>>>(cp[0], cp[14], cp[15], w1t, cp[17], cp[18], xw1, esed);
  alpha_k<<<128,256,0,stream>>>(esed, alph);
  agg8_k<64><<<13312,256,0,stream>>>(xw1, alph, cp[19], h1);
  gat_dense2_k<<<6656,256,0,stream>>>(h1, w2t, cp[21], cp[22], xw2, esed);
  alpha_k<<<128,256,0,stream>>>(esed, alph);
  agg8_k<32><<<6656,256,0,stream>>>(xw2, alph, cp[23], h2);

  // ---- ta-branch x-projection ----
  gemm_embed_mfma_k<false><<<dim3(256,2,1),256,0,stream>>>(cp[3], cp[4], cp[5], cp[6], h2,
      cp[24],cp[25],cp[26],cp[27],cp[28],cp[29],cp[30],cp[31], cp[36], xwta, 0);

  // ---- combined: ta lstm64 (128 blocks) + enc gate-split LSTM (1536 blocks) ----
  enc_ta_mega_k<<<1664,512,0,stream>>>(cp[7], cp[8], cp[9], cp[10], h2,
      cp[24],cp[25],cp[26],cp[27],cp[28],cp[29],cp[30],cp[31],
      cp[32], wench, cp[34], cp[35], hst,
      xwta, wtah, cp[38], cp[39], hsta);

  // ---- fused social conv + inline temporal attention + enc build ----
  fused_conv_k<<<512,256,0,stream>>>(hst, wp1t, wp2t, cp[45], cp[47],
      hsta, cp[40], cp[41], cp[42], cp[43],
      cp[12], cp[13], e192, encd);

  // ---- merged heads: dec projection GEMM + lat/lon softmax ----
  head_k<<<72,256,0,stream>>>(encd, cp[48], xwd, 512, 197,
      e192, cp[54], cp[55], cp[56], cp[57], out, flag);

  // ---- dec LSTM with fused output projection ----
  lstm128_out_k<<<128,512,0,stream>>>(xwd, wdech, cp[50], cp[51], NTOUT,
      cp[52], cp[53], out, flag);
}

// Round 15
// 717.121 us; speedup vs baseline: 1.0191x; 1.0191x over previous
//
#include <hip/hip_runtime.h>
#include <hip/hip_bf16.h>
#include <cstddef>
#include <cstdint>
#include <math.h>

typedef __hip_bfloat16 bf16;
typedef _Float16 f16;
typedef _Float16 f16x8 __attribute__((ext_vector_type(8)));
typedef _Float16 f16x2 __attribute__((ext_vector_type(2)));
typedef float f32x4 __attribute__((ext_vector_type(4)));
#define MFMA16(a,b,c) __builtin_amdgcn_mfma_f32_16x16x32_f16(a,b,c,0,0,0)

#define DEV __device__ __forceinline__
DEV float bff(bf16 x){ return __bfloat162float(x); }
DEV bf16 fbf(float x){ return __float2bfloat16(x); }
DEV float lr01(float x){ return x>0.f? x : 0.1f*x; }
DEV float lr02(float x){ return x>0.f? x : 0.2f*x; }
DEV float frcp(float x){ return __builtin_amdgcn_rcpf(x); }
DEV float sigm(float x){ return frcp(1.f+__expf(-x)); }
DEV float tanhe(float x){ float a=fabsf(x); float e=__expf(-2.f*a); float t=(1.f-e)*frcp(1.f+e); return x<0.f? -t : t; }
DEV void stout(void* out, int isf, size_t i, float v){
  if (isf) ((float*)out)[i] = v; else ((bf16*)out)[i] = fbf(v);
}
// bf16 bits (low 16 of u) -> float, no memory round-trip
DEV float bfu_lo(unsigned u){ return __uint_as_float(u << 16); }
DEV float bfu_hi(unsigned u){ return __uint_as_float(u & 0xffff0000u); }
DEV float ldr(const void* p, size_t i, int isf){
  return isf ? ((const float*)p)[i] : bff(((const bf16*)p)[i]);
}

// problem constants
#define NBATCH 2048
#define TSEQ 16
#define KNB 12
#define NGRP 32768
#define NNODES 425984
#define NBK 24576
#define NTOUT 25

// ---------------- dtype detect ----------------
__global__ __launch_bounds__(256) void detect_k(const uint32_t* __restrict__ x, int* __restrict__ flag) {
  __shared__ int cnt;
  if (threadIdx.x == 0) cnt = 0;
  __syncthreads();
  float v = __uint_as_float(x[threadIdx.x]);
  float a = fabsf(v);
  if (a > 1e-12f && a < 100.f) atomicAdd(&cnt, 1);
  __syncthreads();
  if (threadIdx.x == 0) *flag = (cnt >= 128) ? 1 : 0;
}

#define NCVT 55
struct CvtArgs {
  const void* src[NCVT];
  unsigned off[NCVT];
  unsigned cnt[NCVT];
};

// ---------------- convert (blocks <4096) + weight repack (blocks >=4096) ----------------
__global__ __launch_bounds__(256) void cvtprep_k(CvtArgs a, float* __restrict__ dst,
    const int* __restrict__ flag, unsigned total,
    const void* __restrict__ scW, const void* __restrict__ c31W,
    const void* __restrict__ g1W, const void* __restrict__ g2W,
    const void* __restrict__ encWhh, const void* __restrict__ taWhh,
    const void* __restrict__ decWhh,
    f16* __restrict__ wp1t, f16* __restrict__ wp2t,
    float* __restrict__ w1t, float* __restrict__ w2t,
    f16* __restrict__ wench, f16* __restrict__ wtah, f16* __restrict__ wdech) {
  const int isf = *flag;
  if (blockIdx.x < 4096) {
    for (size_t e = (size_t)blockIdx.x*256 + threadIdx.x; e < total; e += (size_t)4096*256) {
      int lo = 0, hi = NCVT-1;
      while (lo < hi) { int mid = (lo+hi+1)>>1; if ((size_t)a.off[mid] <= e) lo = mid; else hi = mid-1; }
      unsigned r = (unsigned)(e - a.off[lo]);
      float v = isf ? ((const float*)a.src[lo])[r] : bff(((const bf16*)a.src[lo])[r]);
      dst[e] = v;
    }
    return;
  }
  int idx = (blockIdx.x - 4096)*256 + threadIdx.x;     // 117,760 total
  if (idx < 12288) {
    int o = idx & 63; int k = idx >> 6; int kh = k >> 6; int i = k & 63;
    wp1t[idx] = (f16)ldr(scW, ((size_t)(o*64+i)*3 + kh)*3, isf);
  } else if (idx < 15360) {
    int e = idx - 12288;
    int o = e & 15; int k = e >> 4; int kh = k >> 6; int i = k & 63;
    wp2t[e] = (f16)ldr(c31W, (size_t)(o*64+i)*3 + kh, isf);
  } else if (idx < 17408) {
    int e = idx - 15360; int k = e >> 6, f = e & 63;
    w1t[e] = ldr(g1W, f*32 + k, isf);
  } else if (idx < 19456) {
    int e = idx - 17408; int k = e >> 5, f = e & 31;
    w2t[e] = ldr(g2W, f*64 + k, isf);
  } else if (idx < 35840) {
    int e = idx - 19456;
    wench[e] = (f16)ldr(encWhh, e, isf);
  } else if (idx < 52224) {
    int e = idx - 35840;
    wtah[e] = (f16)ldr(taWhh, e, isf);
  } else if (idx < 117760) {
    int e = idx - 52224;
    wdech[e] = (f16)ldr(decWhh, e, isf);
  }
}

// ---------------- GAT layer 1: ip_emb + dense(32->64) + esed fused ----------------
__global__ __launch_bounds__(256) void gat_dense1_k(const float* __restrict__ x,
    const float* __restrict__ ipW, const float* __restrict__ ipb,
    const float* __restrict__ Wt, const float* __restrict__ as_, const float* __restrict__ ad_,
    bf16* __restrict__ out, float* __restrict__ esed) {
  __shared__ float As[64][33];
  __shared__ float Ws[32][64];
  __shared__ float xs[64][4];
  __shared__ float wipw[128];
  __shared__ float wipb[32];
  const int tid = threadIdx.x;
  const size_t bm = (size_t)blockIdx.x * 64;
  ((float*)xs)[tid] = x[bm*4 + tid];
  if (tid < 128) wipw[tid] = ipW[tid];
  else if (tid < 160) wipb[tid-128] = ipb[tid-128];
  #pragma unroll
  for (int i = 0; i < 8; i++) ((float*)Ws)[tid + 256*i] = Wt[tid + 256*i];
  __syncthreads();
  #pragma unroll
  for (int i = 0; i < 8; i++) {
    int e = tid + 256*i; int v = e >> 5, f = e & 31;
    float a = wipb[f];
    #pragma unroll
    for (int k = 0; k < 4; k++) a += xs[v][k]*wipw[f*4+k];
    As[v][f] = lr01(a);
  }
  __syncthreads();
  const int v = tid >> 2, f0 = (tid & 3) * 16;
  float acc[16];
  #pragma unroll
  for (int i = 0; i < 16; i++) acc[i] = 0.f;
  #pragma unroll 8
  for (int k = 0; k < 32; k++) {
    float a = As[v][k];
    const float4* wr = (const float4*)&Ws[k][f0];
    #pragma unroll
    for (int q = 0; q < 4; q++) {
      float4 w4 = wr[q];
      acc[4*q+0] += a*w4.x; acc[4*q+1] += a*w4.y; acc[4*q+2] += a*w4.z; acc[4*q+3] += a*w4.w;
    }
  }
  bf16* op = out + (bm+v)*64 + f0;
  #pragma unroll
  for (int i = 0; i < 16; i++) op[i] = fbf(acc[i]);
  float es = 0.f, ed = 0.f;
  #pragma unroll
  for (int i = 0; i < 16; i++) { es += acc[i]*as_[f0+i]; ed += acc[i]*ad_[f0+i]; }
  es += __shfl_xor(es, 1); es += __shfl_xor(es, 2);
  ed += __shfl_xor(ed, 1); ed += __shfl_xor(ed, 2);
  if ((tid & 3) == 0) { esed[(bm+v)*2] = es; esed[(bm+v)*2+1] = ed; }
}

// ---------------- GAT layer 2: dense(64->32) + esed fused ----------------
__global__ __launch_bounds__(256) void gat_dense2_k(const bf16* __restrict__ in,
    const float* __restrict__ Wt, const float* __restrict__ as_, const float* __restrict__ ad_,
    bf16* __restrict__ out, float* __restrict__ esed) {
  __shared__ float As[64][65];
  __shared__ float Ws[64][32];
  const int tid = threadIdx.x;
  const size_t bm = (size_t)blockIdx.x * 64;
  #pragma unroll
  for (int i = 0; i < 16; i++) {
    int lin = tid + 256*i;
    As[lin>>6][lin&63] = bff(in[bm*64 + lin]);
    if (i < 8) ((float*)Ws)[tid + 256*i] = Wt[tid + 256*i];
  }
  __syncthreads();
  const int v = tid >> 2, f0 = (tid & 3) * 8;
  float acc[8];
  #pragma unroll
  for (int i = 0; i < 8; i++) acc[i] = 0.f;
  #pragma unroll 8
  for (int k = 0; k < 64; k++) {
    float a = As[v][k];
    const float4* wr = (const float4*)&Ws[k][f0];
    #pragma unroll
    for (int q = 0; q < 2; q++) {
      float4 w4 = wr[q];
      acc[4*q+0] += a*w4.x; acc[4*q+1] += a*w4.y; acc[4*q+2] += a*w4.z; acc[4*q+3] += a*w4.w;
    }
  }
  bf16* op = out + (bm+v)*32 + f0;
  #pragma unroll
  for (int i = 0; i < 8; i++) op[i] = fbf(acc[i]);
  float es = 0.f, ed = 0.f;
  #pragma unroll
  for (int i = 0; i < 8; i++) { es += acc[i]*as_[f0+i]; ed += acc[i]*ad_[f0+i]; }
  es += __shfl_xor(es, 1); es += __shfl_xor(es, 2);
  ed += __shfl_xor(ed, 1); ed += __shfl_xor(ed, 2);
  if ((tid & 3) == 0) { esed[(bm+v)*2] = es; esed[(bm+v)*2+1] = ed; }
}

__global__ __launch_bounds__(256) void alpha_k(const float* __restrict__ esed, float* __restrict__ alph) {
  int g = blockIdx.x*256 + threadIdx.x;                // NGRP
  size_t base = (size_t)g*13;
  float esv[13], edv[13];
  #pragma unroll
  for (int i = 0; i < 13; i++) { esv[i] = esed[(base+i)*2]; edv[i] = esed[(base+i)*2+1]; }
  float* o = alph + (size_t)g*40;
  float e[13]; float m = -1e30f;
  #pragma unroll
  for (int i = 0; i < 13; i++) { float z = lr02(esv[i] + edv[0]); e[i] = z; m = fmaxf(m, z); }
  float den = 0.f;
  #pragma unroll
  for (int i = 0; i < 13; i++) { e[i] = __expf(e[i]-m); den += e[i]; }
  float inv = 1.f/den;
  #pragma unroll
  for (int i = 0; i < 13; i++) o[i] = e[i]*inv;
  #pragma unroll
  for (int j = 1; j <= 12; j++) {
    float z0 = lr02(esv[0] + edv[j]);
    float z1 = lr02(esv[j] + edv[j]);
    float mm = fmaxf(z0, z1);
    float a0 = __expf(z0-mm), a1 = __expf(z1-mm);
    float s = 1.f/(a0+a1);
    o[13 + 2*(j-1)] = a0*s;
    o[14 + 2*(j-1)] = a1*s;
  }
}

// ---------------- GAT aggregate, vectorized 8 f per thread (16B loads) ----------------
template<int F>
__global__ __launch_bounds__(256) void agg8_k(const bf16* __restrict__ xw, const float* __restrict__ alph,
                                              const float* __restrict__ bias, bf16* __restrict__ out) {
  const int NV = F/8;
  size_t idx = (size_t)blockIdx.x*256 + threadIdx.x;   // NNODES * F/8
  int f8 = (int)(idx % NV);
  size_t vn = idx / NV;
  int node = (int)(vn % 13);
  size_t g = vn / 13;
  size_t base = g*13;
  const float* al = alph + g*40;
  const int f0 = f8*8;
  float acc[8];
  if (node == 0) {
    #pragma unroll
    for (int j = 0; j < 8; j++) acc[j] = 0.f;
    #pragma unroll
    for (int i = 0; i < 13; i++) {
      const uint4 rv = *(const uint4*)&xw[(base+i)*F + f0];
      float a = al[i];
      acc[0] += a*bfu_lo(rv.x); acc[1] += a*bfu_hi(rv.x);
      acc[2] += a*bfu_lo(rv.y); acc[3] += a*bfu_hi(rv.y);
      acc[4] += a*bfu_lo(rv.z); acc[5] += a*bfu_hi(rv.z);
      acc[6] += a*bfu_lo(rv.w); acc[7] += a*bfu_hi(rv.w);
    }
  } else {
    float a0 = al[13 + 2*(node-1)], a1 = al[14 + 2*(node-1)];
    const uint4 r0v = *(const uint4*)&xw[base*F + f0];
    const uint4 r1v = *(const uint4*)&xw[(base+node)*F + f0];
    acc[0] = a0*bfu_lo(r0v.x) + a1*bfu_lo(r1v.x);
    acc[1] = a0*bfu_hi(r0v.x) + a1*bfu_hi(r1v.x);
    acc[2] = a0*bfu_lo(r0v.y) + a1*bfu_lo(r1v.y);
    acc[3] = a0*bfu_hi(r0v.y) + a1*bfu_hi(r1v.y);
    acc[4] = a0*bfu_lo(r0v.z) + a1*bfu_lo(r1v.z);
    acc[5] = a0*bfu_hi(r0v.z) + a1*bfu_hi(r1v.z);
    acc[6] = a0*bfu_lo(r0v.w) + a1*bfu_lo(r1v.w);
    acc[7] = a0*bfu_hi(r0v.w) + a1*bfu_hi(r1v.w);
  }
  bf16* op = out + vn*F + f0;
  #pragma unroll
  for (int j = 0; j < 8; j++) op[j] = fbf(lr01(acc[j] + bias[f0+j]));
}

// ---------------- fused embed + MFMA GEMM (ta branch): C[m][n] = x_row(m)@W[n][:], K=144 pad 160 ----------------
template<bool NBR>
__global__ __launch_bounds__(256) void gemm_embed_mfma_k(
    const float* __restrict__ p_in, const float* __restrict__ v_in,
    const float* __restrict__ di_in, const float* __restrict__ l_in,
    const bf16* __restrict__ h2,
    const float* __restrict__ posW, const float* __restrict__ posb,
    const float* __restrict__ vaW, const float* __restrict__ vab,
    const float* __restrict__ disW, const float* __restrict__ disb,
    const float* __restrict__ laneW, const float* __restrict__ laneb,
    const float* __restrict__ W, f16* __restrict__ C, int t0) {
  __shared__ __align__(16) f16 As[128][40];
  __shared__ __align__(16) f16 Bs[128][40];
  const int tid = threadIdx.x;
  const int bm = blockIdx.x * 128, bn = blockIdx.y * 128;
  const int bz = blockIdx.z;
  const int mm = tid & 127, par = tid >> 7;
  int t, n2;
  if (NBR) { t = t0 + bz; n2 = bm + mm; }
  else { int gm = bm + mm; t = gm >> 11; n2 = gm & 2047; }
  const int NROW = NBR ? NBK : NBATCH;
  size_t rn = (size_t)t*NROW + n2;
  const float px0 = p_in[rn*2], px1 = p_in[rn*2+1];
  const float vx0 = v_in[rn*2], vx1 = v_in[rn*2+1];
  const float dx  = di_in[rn];
  const float lx0 = l_in[rn*2], lx1 = l_in[rn*2+1];
  const int b = NBR ? (n2 / KNB) : n2;
  const int node_off = NBR ? (1 + n2 % KNB) : 0;
  const bf16* h2p = h2 + (((size_t)t*NBATCH + b)*13 + node_off)*32;
  const int wn = bn + mm;
  const int l = tid & 63, wv = tid >> 6;
  const int lr = l & 15, lq = l >> 4;
  f32x4 acc[2][8];
  #pragma unroll
  for (int rt = 0; rt < 2; rt++)
    #pragma unroll
    for (int ct = 0; ct < 8; ct++) acc[rt][ct] = (f32x4){0.f,0.f,0.f,0.f};
  for (int ks = 0; ks < 5; ks++) {
    const int k0 = ks*32;
    #pragma unroll
    for (int e = 0; e < 16; e++) {
      int kk = par + 2*e;
      int f = k0 + kk;
      float val;
      if (f < 32) {
        val = lr01(px0*posW[f*2] + px1*posW[f*2+1] + posb[f]);
      } else if (f < 64) {
        int ff = f-32;
        val = lr01(vx0*vaW[ff*2] + vx1*vaW[ff*2+1] + vab[ff]);
      } else if (f < 80) {
        int ff = f-64;
        val = lr01(dx*disW[ff] + disb[ff]);
      } else if (f < 112) {
        int ff = f-80;
        val = lr01(lx0*laneW[ff*2] + lx1*laneW[ff*2+1] + laneb[ff]);
      } else if (f < 144) {
        val = bff(h2p[f-112]);
      } else val = 0.f;
      As[mm][kk] = (f16)val;
      Bs[mm][kk] = (f < 144) ? (f16)W[(size_t)wn*144 + f] : (f16)0.f;
    }
    __syncthreads();
    f16x8 a0 = *(const f16x8*)&As[wv*32 + lr][lq*8];
    f16x8 a1 = *(const f16x8*)&As[wv*32 + 16 + lr][lq*8];
    #pragma unroll
    for (int ct = 0; ct < 8; ct++) {
      f16x8 bfr = *(const f16x8*)&Bs[ct*16 + lr][lq*8];
      acc[0][ct] = MFMA16(a0, bfr, acc[0][ct]);
      acc[1][ct] = MFMA16(a1, bfr, acc[1][ct]);
    }
    __syncthreads();
  }
  #pragma unroll
  for (int rt = 0; rt < 2; rt++)
    #pragma unroll
    for (int ct = 0; ct < 8; ct++)
      #pragma unroll
      for (int rg = 0; rg < 4; rg++) {
        int row = wv*32 + rt*16 + lq*4 + rg;
        int col = ct*16 + lr;
        size_t orow = NBR ? ((size_t)bz*NBK + bm + row) : (size_t)(bm + row);
        C[orow*256 + bn + col] = (f16)acc[rt][ct][rg];
      }
}

// ---------------- combined enc(v8 gate-split) + ta-lstm64 mega kernel ----------------
__global__ __launch_bounds__(512, 4) void enc_ta_mega_k(
    const float* __restrict__ p_in, const float* __restrict__ v_in,
    const float* __restrict__ di_in, const float* __restrict__ l_in,
    const bf16* __restrict__ h2,
    const float* __restrict__ posW, const float* __restrict__ posb,
    const float* __restrict__ vaW, const float* __restrict__ vab,
    const float* __restrict__ disW, const float* __restrict__ disb,
    const float* __restrict__ laneW, const float* __restrict__ laneb,
    const float* __restrict__ Wih, const f16* __restrict__ Whh16,
    const float* __restrict__ bih, const float* __restrict__ bhh,
    float* __restrict__ hstate,
    const f16* __restrict__ XWta, const f16* __restrict__ Whh16ta,
    const float* __restrict__ bihta, const float* __restrict__ bhhta,
    float* __restrict__ h_all_ta) {
  __shared__ __align__(16) union SMem {
    struct { f16 As_s[2][16][168]; f16 h_s[2][16][72]; float gates[16][258]; } e;
    struct { f16 h_s[16][72]; float gates[16][260]; } a;
  } sm;
  const int tid = threadIdx.x;
  const int l = tid & 63;
  const int lr = l & 15, lq = l >> 4;

  if (blockIdx.x < 128) {
    // ================= ta lstm64 path (t0=0, TSEQ steps, nrows=NBATCH) =================
    const int r0 = blockIdx.x * 16;
    const int wv = tid >> 6;           // 0..7; waves 0..3 active
    const int u = l, rg = wv;
    f16x8 bf[4][2];
    if (wv < 4) {
      #pragma unroll
      for (int ct = 0; ct < 4; ct++)
        #pragma unroll
        for (int kt = 0; kt < 2; kt++)
          bf[ct][kt] = *(const f16x8*)&Whh16ta[(size_t)(wv*64 + ct*16 + lr)*64 + kt*32 + lq*8];
    }
    float bj4[4];
    #pragma unroll
    for (int g = 0; g < 4; g++) bj4[g] = bihta[g*64+u] + bhhta[g*64+u];
    for (int i = tid; i < 16*64; i += 512) sm.a.h_s[i>>6][i&63] = (f16)0.f;
    float c[4] = {0.f,0.f,0.f,0.f};
    __syncthreads();
    #pragma unroll 1
    for (int s = 0; s < TSEQ; s++) {
      if (wv < 4) {
        f16x8 a0 = *(const f16x8*)&sm.a.h_s[lr][lq*8];
        f16x8 a1 = *(const f16x8*)&sm.a.h_s[lr][32 + lq*8];
        f32x4 acc[4];
        #pragma unroll
        for (int ct = 0; ct < 4; ct++) {
          acc[ct] = (f32x4){0.f,0.f,0.f,0.f};
          acc[ct] = MFMA16(a0, bf[ct][0], acc[ct]);
          acc[ct] = MFMA16(a1, bf[ct][1], acc[ct]);
        }
        #pragma unroll
        for (int ct = 0; ct < 4; ct++)
          #pragma unroll
          for (int q2 = 0; q2 < 4; q2++)
            sm.a.gates[lq*4 + q2][wv*64 + ct*16 + lr] = acc[ct][q2];
      }
      __syncthreads();
      if (wv < 4) {
        const f16* xwrow = XWta + ((size_t)s*NBATCH + r0)*256;
        #pragma unroll
        for (int q = 0; q < 4; q++) {
          const int r = rg*4 + q;
          float gi = sm.a.gates[r][u]     + bj4[0] + (float)xwrow[(size_t)r*256 + u];
          float gf = sm.a.gates[r][64+u]  + bj4[1] + (float)xwrow[(size_t)r*256 + 64 + u];
          float gg = sm.a.gates[r][128+u] + bj4[2] + (float)xwrow[(size_t)r*256 + 128 + u];
          float go = sm.a.gates[r][192+u] + bj4[3] + (float)xwrow[(size_t)r*256 + 192 + u];
          float cv = sigm(gf)*c[q] + sigm(gi)*tanhe(gg);
          c[q] = cv;
          float hv = sigm(go)*tanhe(cv);
          sm.a.h_s[r][u] = (f16)hv;
          h_all_ta[((size_t)s*NBATCH + r0 + r)*64 + u] = hv;
        }
      }
      __syncthreads();
    }
    return;
  }

  // ================= enc path =================
  const int r0 = (blockIdx.x - 128) * 16;
  const int w = tid >> 6;              // 8 waves
  const int cu0 = w*16 + lr;
  const int cu1 = 128 + cu0;
  f16x8 bxw[2][5];
  f16x8 bhw[2][2];
  float bv[2];
  #pragma unroll
  for (int s = 0; s < 2; s++) {
    const int cu = s ? cu1 : cu0;
    const float* wr = Wih + (size_t)cu*144;
    #pragma unroll
    for (int ks = 0; ks < 5; ks++) {
      f16x8 v;
      #pragma unroll
      for (int j = 0; j < 8; j++) {
        int k = ks*32 + lq*8 + j;
        v[j] = (k < 144) ? (f16)wr[k] : (f16)0.f;
      }
      bxw[s][ks] = v;
    }
    #pragma unroll
    for (int kt = 0; kt < 2; kt++)
      bhw[s][kt] = *(const f16x8*)&Whh16[(size_t)cu*64 + kt*32 + lq*8];
    bv[s] = bih[cu] + bhh[cu];
  }
  const int prow = tid & 15;
  const int pq = tid >> 4;
  const int n2 = r0 + prow;
  const int bb = n2 / KNB;
  const int noff = 1 + n2 - bb*KNB;
  float c0 = 0.f, c1 = 0.f;
  float La = 0.f, Lb = 0.f;
  uint4 HA = {0,0,0,0};
  for (int i = tid; i < 16*64; i += 512) sm.e.h_s[0][i>>6][i&63] = (f16)0.f;

#define ENC_ISSUE(TP) do {                                                   \
    const size_t rnp = (size_t)(TP)*NBK + n2;                                \
    if (pq < 4)       { float2 p = *(const float2*)(p_in + rnp*2); La = p.x; Lb = p.y; } \
    else if (pq < 8)  { float2 p = *(const float2*)(v_in + rnp*2); La = p.x; Lb = p.y; } \
    else if (pq < 10) { La = di_in[rnp]; }                                   \
    else if (pq < 14) { float2 p = *(const float2*)(l_in + rnp*2); La = p.x; Lb = p.y; } \
    else if (pq < 18) { HA = *(const uint4*)(h2 + (((size_t)(TP)*NBATCH + bb)*13 + noff)*32 + (pq-14)*8); } \
  } while (0)

#define ENC_STAGE(BUF) do {                                                  \
    if (pq < 20) {                                                           \
      const int f0 = pq*8;                                                   \
      f16x8 v;                                                               \
      if (f0 < 32) {                                                         \
        _Pragma("unroll")                                                    \
        for (int j = 0; j < 8; j++)                                          \
          v[j] = (f16)lr01(La*posW[(f0+j)*2] + Lb*posW[(f0+j)*2+1] + posb[f0+j]); \
      } else if (f0 < 64) {                                                  \
        _Pragma("unroll")                                                    \
        for (int j = 0; j < 8; j++) {                                        \
          int ff = f0+j-32;                                                  \
          v[j] = (f16)lr01(La*vaW[ff*2] + Lb*vaW[ff*2+1] + vab[ff]);         \
        }                                                                    \
      } else if (f0 < 80) {                                                  \
        _Pragma("unroll")                                                    \
        for (int j = 0; j < 8; j++) {                                        \
          int ff = f0+j-64;                                                  \
          v[j] = (f16)lr01(La*disW[ff] + disb[ff]);                          \
        }                                                                    \
      } else if (f0 < 112) {                                                 \
        _Pragma("unroll")                                                    \
        for (int j = 0; j < 8; j++) {                                        \
          int ff = f0+j-80;                                                  \
          v[j] = (f16)lr01(La*laneW[ff*2] + Lb*laneW[ff*2+1] + laneb[ff]);   \
        }                                                                    \
      } else if (f0 < 144) {                                                 \
        v[0] = (f16)bfu_lo(HA.x); v[1] = (f16)bfu_hi(HA.x);                  \
        v[2] = (f16)bfu_lo(HA.y); v[3] = (f16)bfu_hi(HA.y);                  \
        v[4] = (f16)bfu_lo(HA.z); v[5] = (f16)bfu_hi(HA.z);                  \
        v[6] = (f16)bfu_lo(HA.w); v[7] = (f16)bfu_hi(HA.w);                  \
      } else {                                                               \
        _Pragma("unroll")                                                    \
        for (int j = 0; j < 8; j++) v[j] = (f16)0.f;                         \
      }                                                                      \
      *(f16x8*)&sm.e.As_s[BUF][prow][f0] = v;                                \
    }                                                                        \
  } while (0)

  ENC_ISSUE(0);
  ENC_STAGE(0);
  __syncthreads();
  int cur = 0;
  #pragma unroll 1
  for (int t = 0; t < TSEQ; t++) {
    const int tp = (t+1 < TSEQ) ? t+1 : t;
    ENC_ISSUE(tp);
    {
      f16x8 ae0 = *(const f16x8*)&sm.e.As_s[cur][lr][lq*8];
      f16x8 ae1 = *(const f16x8*)&sm.e.As_s[cur][lr][32 + lq*8];
      f16x8 ae2 = *(const f16x8*)&sm.e.As_s[cur][lr][64 + lq*8];
      f16x8 ae3 = *(const f16x8*)&sm.e.As_s[cur][lr][96 + lq*8];
      f16x8 ae4 = *(const f16x8*)&sm.e.As_s[cur][lr][128 + lq*8];
      f16x8 ah0 = *(const f16x8*)&sm.e.h_s[cur][lr][lq*8];
      f16x8 ah1 = *(const f16x8*)&sm.e.h_s[cur][lr][32 + lq*8];
      #pragma unroll
      for (int s = 0; s < 2; s++) {
        f32x4 a = (f32x4){0.f,0.f,0.f,0.f};
        a = MFMA16(ae0, bxw[s][0], a);
        a = MFMA16(ae1, bxw[s][1], a);
        a = MFMA16(ae2, bxw[s][2], a);
        a = MFMA16(ae3, bxw[s][3], a);
        a = MFMA16(ae4, bxw[s][4], a);
        a = MFMA16(ah0, bhw[s][0], a);
        a = MFMA16(ah1, bhw[s][1], a);
        const int cu = s ? cu1 : cu0;
        #pragma unroll
        for (int q = 0; q < 4; q++)
          sm.e.gates[lq*4 + q][cu] = a[q] + bv[s];
      }
    }
    __syncthreads();
    {
      const int u0 = pq*2;
      const float* gr = &sm.e.gates[prow][0];
      float gi0 = gr[u0],       gi1 = gr[u0+1];
      float gf0 = gr[64+u0],    gf1 = gr[64+u0+1];
      float gg0 = gr[128+u0],   gg1 = gr[128+u0+1];
      float go0 = gr[192+u0],   go1 = gr[192+u0+1];
      float cv0 = sigm(gf0)*c0 + sigm(gi0)*tanhe(gg0);
      float cv1 = sigm(gf1)*c1 + sigm(gi1)*tanhe(gg1);
      c0 = cv0; c1 = cv1;
      f16x2 hv;
      hv[0] = (f16)(sigm(go0)*tanhe(cv0));
      hv[1] = (f16)(sigm(go1)*tanhe(cv1));
      *(f16x2*)&sm.e.h_s[cur^1][prow][u0] = hv;
    }
    ENC_STAGE(cur^1);
    __syncthreads();
    cur ^= 1;
  }
#undef ENC_ISSUE
#undef ENC_STAGE
  for (int i = tid; i < 16*64; i += 512)
    hstate[(size_t)(r0 + (i>>6))*64 + (i&63)] = (float)sm.e.h_s[cur][i>>6][i&63];
}

// ---------------- merged heads: gemm_bt (blocks 0..63) + latlon (blocks 64..71) ----------------
__global__ __launch_bounds__(256, 2) void head_k(const bf16* __restrict__ A, const float* __restrict__ W,
    float* __restrict__ C, int N, int Kd,
    const float* __restrict__ e192,
    const float* __restrict__ latW, const float* __restrict__ latb,
    const float* __restrict__ lonW, const float* __restrict__ lonb,
    void* __restrict__ out, const int* __restrict__ flag) {
  const int tid = threadIdx.x;
  if (blockIdx.x < 64) {
    __shared__ __align__(16) float As[8][132];
    __shared__ __align__(16) float Bs[8][132];
    const int bm = (blockIdx.x >> 2) * 128, bn = (blockIdx.x & 3) * 128;
    const int tx = tid & 15, ty = tid >> 4;
    float acc[8][8];
    #pragma unroll
    for (int i = 0; i < 8; i++)
      #pragma unroll
      for (int j = 0; j < 8; j++) acc[i][j] = 0.f;
    for (int k0 = 0; k0 < Kd; k0 += 8) {
      #pragma unroll
      for (int i = 0; i < 4; i++) {
        int lin = tid + 256*i;
        int kk = lin & 7, mm = lin >> 3;
        int gk = k0 + kk;
        As[kk][mm] = (gk < Kd) ? bff(A[(size_t)(bm+mm)*Kd + gk]) : 0.f;
        Bs[kk][mm] = (gk < Kd) ? W[(size_t)(bn+mm)*Kd + gk] : 0.f;
      }
      __syncthreads();
      #pragma unroll
      for (int kk = 0; kk < 8; kk++) {
        float4 a0 = *(const float4*)&As[kk][ty*4];
        float4 a1 = *(const float4*)&As[kk][64+ty*4];
        float4 b0 = *(const float4*)&Bs[kk][tx*4];
        float4 b1 = *(const float4*)&Bs[kk][64+tx*4];
        float av[8] = {a0.x,a0.y,a0.z,a0.w,a1.x,a1.y,a1.z,a1.w};
        float bvv[8] = {b0.x,b0.y,b0.z,b0.w,b1.x,b1.y,b1.z,b1.w};
        #pragma unroll
        for (int i = 0; i < 8; i++)
          #pragma unroll
          for (int j = 0; j < 8; j++) acc[i][j] += av[i]*bvv[j];
      }
      __syncthreads();
    }
    #pragma unroll
    for (int i = 0; i < 8; i++) {
      int m = bm + (i>>2)*64 + ty*4 + (i&3);
      #pragma unroll
      for (int jh = 0; jh < 2; jh++) {
        float4 v = make_float4(acc[i][jh*4+0], acc[i][jh*4+1], acc[i][jh*4+2], acc[i][jh*4+3]);
        *(float4*)&C[(size_t)m*N + bn + jh*64 + tx*4] = v;
      }
    }
  } else {
    int b = (blockIdx.x - 64)*256 + tid;               // NBATCH
    const int isf = *flag;
    const float* e = e192 + (size_t)b*192;
    float s[3];
    #pragma unroll
    for (int c2 = 0; c2 < 3; c2++) {
      float acc = latb[c2];
      for (int k = 0; k < 192; k++) acc += e[k]*latW[c2*192+k];
      s[c2] = acc;
    }
    float m = fmaxf(s[0], fmaxf(s[1], s[2]));
    float e0 = __expf(s[0]-m), e1 = __expf(s[1]-m), e2 = __expf(s[2]-m);
    float inv = 1.f/(e0+e1+e2);
    stout(out, isf, 256000 + (size_t)b*3 + 0, e0*inv);
    stout(out, isf, 256000 + (size_t)b*3 + 1, e1*inv);
    stout(out, isf, 256000 + (size_t)b*3 + 2, e2*inv);
    float q[2];
    #pragma unroll
    for (int c2 = 0; c2 < 2; c2++) {
      float acc = lonb[c2];
      for (int k = 0; k < 192; k++) acc += e[k]*lonW[c2*192+k];
      q[c2] = acc;
    }
    float m2 = fmaxf(q[0], q[1]);
    float f0 = __expf(q[0]-m2), f1 = __expf(q[1]-m2);
    float inv2 = 1.f/(f0+f1);
    stout(out, isf, 262144 + (size_t)b*2 + 0, f0*inv2);
    stout(out, isf, 262144 + (size_t)b*2 + 1, f1*inv2);
  }
}

// ---------------- MFMA LSTM H=128 (dec) + fused output projection ----------------
__global__ __launch_bounds__(512) void lstm128_out_k(const float* __restrict__ XW,
    const f16* __restrict__ Whh16, const float* __restrict__ bih, const float* __restrict__ bhh,
    int steps, const float* __restrict__ opW, const float* __restrict__ opb,
    void* __restrict__ out, const int* __restrict__ flag) {
  __shared__ __align__(16) f16 h_s[2][16][136];
  __shared__ float hsf[2][16][132];
  __shared__ float opWs[640];
  __shared__ float opbs[5];
  const int tid = threadIdx.x;
  const int r0 = blockIdx.x * 16;
  const int l = tid & 63, wv = tid >> 6;
  const int lr = l & 15, lq = l >> 4;
  const int u = wv*16 + lr;
  const int isf = *flag;
  f16x8 bf[4][4];
  #pragma unroll
  for (int g = 0; g < 4; g++)
    #pragma unroll
    for (int kt = 0; kt < 4; kt++)
      bf[g][kt] = *(const f16x8*)&Whh16[(size_t)(g*128 + u)*128 + kt*32 + lq*8];
  float xr[4][4];
  #pragma unroll
  for (int g = 0; g < 4; g++) {
    float bj = bih[g*128 + u] + bhh[g*128 + u];
    #pragma unroll
    for (int rg = 0; rg < 4; rg++)
      xr[g][rg] = XW[(size_t)(r0 + lq*4 + rg)*512 + g*128 + u] + bj;
  }
  for (int i = tid; i < 16*128; i += 512) h_s[0][i>>7][i&127] = (f16)0.f;
  for (int i = tid; i < 640; i += 512) opWs[i] = opW[i];
  if (tid < 5) opbs[tid] = opb[tid];
  float c[4] = {0.f,0.f,0.f,0.f};
  __syncthreads();
  int cur = 0;
  #pragma unroll 1
  for (int t = 0; t < steps; t++) {
    f16x8 a0 = *(const f16x8*)&h_s[cur][lr][lq*8];
    f16x8 a1 = *(const f16x8*)&h_s[cur][lr][32 + lq*8];
    f16x8 a2 = *(const f16x8*)&h_s[cur][lr][64 + lq*8];
    f16x8 a3 = *(const f16x8*)&h_s[cur][lr][96 + lq*8];
    f32x4 acc[4];
    #pragma unroll
    for (int g = 0; g < 4; g++) {
      acc[g] = (f32x4){0.f,0.f,0.f,0.f};
      acc[g] = MFMA16(a0, bf[g][0], acc[g]);
      acc[g] = MFMA16(a1, bf[g][1], acc[g]);
      acc[g] = MFMA16(a2, bf[g][2], acc[g]);
      acc[g] = MFMA16(a3, bf[g][3], acc[g]);
    }
    #pragma unroll
    for (int rg = 0; rg < 4; rg++) {
      const int row = lq*4 + rg;
      float gi = acc[0][rg] + xr[0][rg];
      float gf = acc[1][rg] + xr[1][rg];
      float gg = acc[2][rg] + xr[2][rg];
      float go = acc[3][rg] + xr[3][rg];
      float cv = sigm(gf)*c[rg] + sigm(gi)*tanhe(gg);
      c[rg] = cv;
      float hv = sigm(go)*tanhe(cv);
      h_s[cur^1][row][u] = (f16)hv;
      hsf[cur^1][row][u] = hv;
    }
    __syncthreads();
    if (tid < 80) {
      const int row = tid / 5, c2 = tid - (tid/5)*5;
      float acc2 = opbs[c2];
      const float* hr = &hsf[cur^1][row][0];
      for (int k = 0; k < 128; k++) acc2 += hr[k]*opWs[c2*128+k];
      size_t oidx = ((size_t)t*NBATCH + r0 + row)*5 + c2;
      float v = (c2 < 2) ? acc2 : (c2 < 4 ? __expf(acc2) : tanhe(acc2));
      stout(out, isf, oidx, v);
    }
    cur ^= 1;
  }
}

// ---------------- fused temporal attention: scores + softmax + context ----------------
__global__ __launch_bounds__(256) void ta_fused_k(const float* __restrict__ hs,
    const float* __restrict__ W, const float* __restrict__ bias,
    const float* __restrict__ dynW, const float* __restrict__ dynb,
    float* __restrict__ henc) {
  __shared__ float hsl[8][1024];
  __shared__ float scl[8][16];
  const int tid = threadIdx.x;
  const int b0 = blockIdx.x * 8;
  for (int i = tid; i < 8*1024; i += 256) {
    int bb = i >> 10, r = i & 1023;
    int t = r >> 6, h = r & 63;
    hsl[bb][r] = hs[((size_t)t*NBATCH + b0 + bb)*64 + h];
  }
  __syncthreads();
  if (tid < 128) {
    int bb = tid >> 4, i = tid & 15;
    float acc = bias[i];
    for (int t = 0; t < 16; t++) {
      const float* hr = &hsl[bb][t*64];
      const float* wr = W + (size_t)i*1024 + t*64;
      #pragma unroll
      for (int h = 0; h < 64; h++) acc += hr[h]*wr[h];
    }
    scl[bb][i] = fmaxf(acc, 0.f);
  }
  __syncthreads();
  {
    int bb = tid >> 5, o = tid & 31;
    const float* s = scl[bb];
    float m = s[0];
    #pragma unroll
    for (int t = 1; t < 16; t++) m = fmaxf(m, s[t]);
    float e[16]; float den = 0.f;
    #pragma unroll
    for (int t = 0; t < 16; t++) { e[t] = __expf(s[t]-m); den += e[t]; }
    float inv = 1.f/den;
    float acc = dynb[o];
    for (int t = 0; t < 16; t++) {
      const float* hr = &hsl[bb][t*64];
      float inner = 0.f;
      #pragma unroll
      for (int h = 0; h < 64; h++) inner += hr[h]*dynW[(size_t)o*64 + h];
      acc += (e[t]*inv)*inner;
    }
    henc[(size_t)(b0+bb)*32 + o] = lr01(acc);
  }
}

// ---------------- fused social conv: conv1 -> conv2 -> pool -> e192/encd ----------------
__global__ __launch_bounds__(256) void fused_conv_k(const float* __restrict__ nenc,
    const f16* __restrict__ wp1t, const f16* __restrict__ wp2t,
    const float* __restrict__ scb, const float* __restrict__ c31b,
    const float* __restrict__ henc, const float* __restrict__ lat_enc, const float* __restrict__ lon_enc,
    float* __restrict__ e192, bf16* __restrict__ encd) {
  __shared__ f16 ws1[12288];
  __shared__ f16 ws2[3072];
  __shared__ float img[4][13][64];
  __shared__ float c1s[4][64][12];
  __shared__ float c2s[4][16][9];
  const int tid = threadIdx.x;
  const int l = tid & 63, wv = tid >> 6;
  const int b = blockIdx.x*4 + wv;
  #pragma unroll
  for (int it = 0; it < 24; it++) ((uint32_t*)ws1)[tid + 256*it] = ((const uint32_t*)wp1t)[tid + 256*it];
  #pragma unroll
  for (int it = 0; it < 6; it++) ((uint32_t*)ws2)[tid + 256*it] = ((const uint32_t*)wp2t)[tid + 256*it];
  #pragma unroll
  for (int it = 0; it < 13; it++)
    img[wv][it][l] = (it < 12) ? nenc[((size_t)b*12 + it)*64 + l] : 0.f;
  __syncthreads();
  {
    const int o = l;
    float acc[11];
    float bv = scb[o];
    #pragma unroll
    for (int h = 0; h < 11; h++) acc[h] = bv;
    for (int k = 0; k < 192; k++) {
      int kh = k >> 6, i = k & 63;
      float w = (float)ws1[k*64 + o];
      const float* ic = img[wv][kh];
      #pragma unroll
      for (int h = 0; h < 11; h++) acc[h] += ic[h*64 + i] * w;
    }
    #pragma unroll
    for (int h = 0; h < 11; h++) c1s[wv][o][h] = lr01(acc[h]);
  }
  __syncthreads();
  if (l < 48) {
    const int o2 = l / 3, jg = l - o2*3;
    float acc[3];
    float bv = c31b[o2];
    #pragma unroll
    for (int m = 0; m < 3; m++) acc[m] = bv;
    for (int k = 0; k < 192; k++) {
      int kh = k >> 6, i = k & 63;
      float w = (float)ws2[k*16 + o2];
      #pragma unroll
      for (int m = 0; m < 3; m++) acc[m] += c1s[wv][i][jg*3 + m + kh] * w;
    }
    #pragma unroll
    for (int m = 0; m < 3; m++) c2s[wv][o2][jg*3 + m] = lr01(acc[m]);
  }
  __syncthreads();
  for (int it = 0; it < 4; it++) {
    int k = l + it*64;
    if (k >= 197) break;
    float val;
    if (k < 192) {
      if (k < 160) {
        bool is_av = (k >= 80);
        int rel = is_av ? (k - 80) : k;
        int o = rel / 5, p = rel - o*5;
        const float* r = c2s[wv][o];
        float v2 = r[2*p];
        if (p == 0) val = is_av ? v2*0.5f : v2;
        else { float v1 = r[2*p-1]; val = is_av ? (v1+v2)*0.5f : fmaxf(v1, v2); }
      } else {
        val = henc[(size_t)b*32 + (k-160)];
      }
      e192[(size_t)b*192 + k] = val;
    } else if (k < 195) {
      val = lat_enc[(size_t)b*3 + (k-192)];
    } else {
      val = lon_enc[(size_t)b*2 + (k-195)];
    }
    encd[(size_t)b*197 + k] = fbf(val);
  }
}

// ---------------- workspace layout (f32-slot offsets) ----------------
static const size_t OFF_H2   = 0;
static const size_t OFF_P    = 6815744;     // h1 (GAT)
static const size_t OFF_Q    = 20447232;    // xw1/xw2 (GAT)
static const size_t OFF_ESED = 34078720;
static const size_t OFF_ALPH = 34930688;    // -> end 36,241,408
static const size_t OFF_XWTA = 6815744;     // f16 (ta phase)
static const size_t OFF_HSTA = 15204352;    // ta phase
static const size_t OFF_HST  = 23691264;
static const size_t OFF_E192 = 28573696;
static const size_t OFF_ENCD = 28966912;
static const size_t OFF_XWD  = 29168640;
static const size_t OFF_HEN  = 35000000;
static const size_t OFF_CVT  = 36241408;
static const size_t OFF_WP1T = 41280000;
static const size_t OFF_WP2T = 41286144;
static const size_t OFF_W1T  = 41287680;
static const size_t OFF_W2T  = 41289728;
static const size_t OFF_WENC = 41291776;    // f16 x 16384
static const size_t OFF_WTAH = 41299968;    // f16 x 16384
static const size_t OFF_WDECH= 41308160;    // f16 x 65536 (32768 slots)
static const size_t OFF_FLAG = 41400000;

extern "C" void kernel_launch(void* const* d_in, const int* in_sizes, int n_in,
                              void* d_out, int out_size, void* d_ws, size_t ws_size,
                              hipStream_t stream) {
  (void)in_sizes; (void)n_in; (void)out_size; (void)ws_size;
  float* ws = (float*)d_ws;
  int* flag = (int*)(ws + OFF_FLAG);

  static const int   cidx[NCVT] = {0,3,4,5,6,7,8,9,10,12,13,
    14,15,16,17,18,19,20,21,22,23,24,25,26,27,28,29,30,31,
    32,33,34,35,36,37,38,39,40,41,42,43,44,45,46,47,
    48,49,50,51,52,53,54,55,56,57};
  static const unsigned ccnt[NCVT] = {1703936,65536,65536,32768,65536,786432,786432,393216,786432,6144,4096,
    128,32,2048,64,64,64,2048,32,32,32,64,32,64,32,16,16,64,32,
    36864,16384,256,256,36864,16384,256,256,16384,16,2048,32,36864,64,3072,16,
    100864,65536,512,512,640,5,576,3,384,2};
  CvtArgs ca;
  unsigned total = 0;
  float* cp[58];
  for (int i = 0; i < NCVT; i++) {
    ca.src[i] = d_in[cidx[i]];
    ca.off[i] = total;
    ca.cnt[i] = ccnt[i];
    cp[cidx[i]] = ws + OFF_CVT + total;
    total += ccnt[i];
  }
  detect_k<<<1,256,0,stream>>>((const uint32_t*)d_in[0], flag);

  void* out = d_out;
  bf16*  h2    = (bf16*)(ws + OFF_H2);
  bf16*  h1    = (bf16*)(ws + OFF_P);
  bf16*  xw1   = (bf16*)(ws + OFF_Q);
  bf16*  xw2   = (bf16*)(ws + OFF_Q);
  float* esed  = ws + OFF_ESED;
  float* alph  = ws + OFF_ALPH;
  f16*   xwta  = (f16*)(ws + OFF_XWTA);
  float* hsta  = ws + OFF_HSTA;
  float* henc  = ws + OFF_HEN;
  float* hst   = ws + OFF_HST;
  float* e192  = ws + OFF_E192;
  bf16*  encd  = (bf16*)(ws + OFF_ENCD);
  float* xwd   = ws + OFF_XWD;
  f16*   wp1t  = (f16*)(ws + OFF_WP1T);
  f16*   wp2t  = (f16*)(ws + OFF_WP2T);
  float* w1t   = ws + OFF_W1T;
  float* w2t   = ws + OFF_W2T;
  f16*   wench = (f16*)(ws + OFF_WENC);
  f16*   wtah  = (f16*)(ws + OFF_WTAH);
  f16*   wdech = (f16*)(ws + OFF_WDECH);

  // ---- convert + weight repack in one kernel ----
  cvtprep_k<<<4556,256,0,stream>>>(ca, ws + OFF_CVT, flag, total,
      d_in[44], d_in[46], d_in[16], d_in[20], d_in[33], d_in[37], d_in[49],
      wp1t, wp2t, w1t, w2t, wench, wtah, wdech);

  // ---- GAT (fused ip_emb+dense1+esed, dense2+esed) ----
  gat_dense1_k<<<6656,256,0,stream>>>(cp[0], cp[14], cp[15], w1t, cp[17], cp[18], xw1, esed);
  alpha_k<<<128,256,0,stream>>>(esed, alph);
  agg8_k<64><<<13312,256,0,stream>>>(xw1, alph, cp[19], h1);
  gat_dense2_k<<<6656,256,0,stream>>>(h1, w2t, cp[21], cp[22], xw2, esed);
  alpha_k<<<128,256,0,stream>>>(esed, alph);
  agg8_k<32><<<6656,256,0,stream>>>(xw2, alph, cp[23], h2);

  // ---- ta-branch x-projection ----
  gemm_embed_mfma_k<false><<<dim3(256,2,1),256,0,stream>>>(cp[3], cp[4], cp[5], cp[6], h2,
      cp[24],cp[25],cp[26],cp[27],cp[28],cp[29],cp[30],cp[31], cp[36], xwta, 0);

  // ---- combined: ta lstm64 (128 blocks) + enc gate-split LSTM (1536 blocks) ----
  enc_ta_mega_k<<<1664,512,0,stream>>>(cp[7], cp[8], cp[9], cp[10], h2,
      cp[24],cp[25],cp[26],cp[27],cp[28],cp[29],cp[30],cp[31],
      cp[32], wench, cp[34], cp[35], hst,
      xwta, wtah, cp[38], cp[39], hsta);

  // ---- fused temporal attention (scores + softmax + ctx) ----
  ta_fused_k<<<256,256,0,stream>>>(hsta, cp[40], cp[41], cp[42], cp[43], henc);

  // ---- fused social conv + pool + enc build ----
  fused_conv_k<<<512,256,0,stream>>>(hst, wp1t, wp2t, cp[45], cp[47], henc, cp[12], cp[13], e192, encd);

  // ---- merged heads: dec projection GEMM + lat/lon softmax ----
  head_k<<<72,256,0,stream>>>(encd, cp[48], xwd, 512, 197,
      e192, cp[54], cp[55], cp[56], cp[57], out, flag);

  // ---- dec LSTM with fused output projection ----
  lstm128_out_k<<<128,512,0,stream>>>(xwd, wdech, cp[50], cp[51], NTOUT,
      cp[52], cp[53], out, flag);
}

// Round 16
// 687.181 us; speedup vs baseline: 1.0635x; 1.0436x over previous
//
#include <hip/hip_runtime.h>
#include <hip/hip_bf16.h>
#include <cstddef>
#include <cstdint>
#include <math.h>

typedef __hip_bfloat16 bf16;
typedef _Float16 f16;
typedef _Float16 f16x8 __attribute__((ext_vector_type(8)));
typedef _Float16 f16x2 __attribute__((ext_vector_type(2)));
typedef float f32x4 __attribute__((ext_vector_type(4)));
#define MFMA16(a,b,c) __builtin_amdgcn_mfma_f32_16x16x32_f16(a,b,c,0,0,0)

#define DEV __device__ __forceinline__
DEV float bff(bf16 x){ return __bfloat162float(x); }
DEV bf16 fbf(float x){ return __float2bfloat16(x); }
DEV float lr01(float x){ return x>0.f? x : 0.1f*x; }
DEV float lr02(float x){ return x>0.f? x : 0.2f*x; }
DEV float frcp(float x){ return __builtin_amdgcn_rcpf(x); }
DEV float sigm(float x){ return frcp(1.f+__expf(-x)); }
DEV float tanhe(float x){ float a=fabsf(x); float e=__expf(-2.f*a); float t=(1.f-e)*frcp(1.f+e); return x<0.f? -t : t; }
DEV void stout(void* out, int isf, size_t i, float v){
  if (isf) ((float*)out)[i] = v; else ((bf16*)out)[i] = fbf(v);
}
// bf16 bits (low 16 of u) -> float, no memory round-trip
DEV float bfu_lo(unsigned u){ return __uint_as_float(u << 16); }
DEV float bfu_hi(unsigned u){ return __uint_as_float(u & 0xffff0000u); }
DEV float ldr(const void* p, size_t i, int isf){
  return isf ? ((const float*)p)[i] : bff(((const bf16*)p)[i]);
}

// problem constants
#define NBATCH 2048
#define TSEQ 16
#define KNB 12
#define NGRP 32768
#define NNODES 425984
#define NBK 24576
#define NTOUT 25

// ---------------- dtype detect ----------------
__global__ __launch_bounds__(256) void detect_k(const uint32_t* __restrict__ x, int* __restrict__ flag) {
  __shared__ int cnt;
  if (threadIdx.x == 0) cnt = 0;
  __syncthreads();
  float v = __uint_as_float(x[threadIdx.x]);
  float a = fabsf(v);
  if (a > 1e-12f && a < 100.f) atomicAdd(&cnt, 1);
  __syncthreads();
  if (threadIdx.x == 0) *flag = (cnt >= 128) ? 1 : 0;
}

#define NCVT 55
struct CvtArgs {
  const void* src[NCVT];
  unsigned off[NCVT];
  unsigned cnt[NCVT];
};

// ---------------- convert (blocks <4096) + weight repack (blocks >=4096) ----------------
__global__ __launch_bounds__(256) void cvtprep_k(CvtArgs a, float* __restrict__ dst,
    const int* __restrict__ flag, unsigned total,
    const void* __restrict__ scW, const void* __restrict__ c31W,
    const void* __restrict__ g1W, const void* __restrict__ g2W,
    const void* __restrict__ encWhh, const void* __restrict__ taWhh,
    const void* __restrict__ decWhh,
    f16* __restrict__ wp1t, f16* __restrict__ wp2t,
    float* __restrict__ w1t, float* __restrict__ w2t,
    f16* __restrict__ wench, f16* __restrict__ wtah, f16* __restrict__ wdech) {
  const int isf = *flag;
  if (blockIdx.x < 4096) {
    for (size_t e = (size_t)blockIdx.x*256 + threadIdx.x; e < total; e += (size_t)4096*256) {
      int lo = 0, hi = NCVT-1;
      while (lo < hi) { int mid = (lo+hi+1)>>1; if ((size_t)a.off[mid] <= e) lo = mid; else hi = mid-1; }
      unsigned r = (unsigned)(e - a.off[lo]);
      float v = isf ? ((const float*)a.src[lo])[r] : bff(((const bf16*)a.src[lo])[r]);
      dst[e] = v;
    }
    return;
  }
  int idx = (blockIdx.x - 4096)*256 + threadIdx.x;     // 117,760 total
  if (idx < 12288) {
    int o = idx & 63; int k = idx >> 6; int kh = k >> 6; int i = k & 63;
    wp1t[idx] = (f16)ldr(scW, ((size_t)(o*64+i)*3 + kh)*3, isf);
  } else if (idx < 15360) {
    int e = idx - 12288;
    int o = e & 15; int k = e >> 4; int kh = k >> 6; int i = k & 63;
    wp2t[e] = (f16)ldr(c31W, (size_t)(o*64+i)*3 + kh, isf);
  } else if (idx < 17408) {
    int e = idx - 15360; int k = e >> 6, f = e & 63;
    w1t[e] = ldr(g1W, f*32 + k, isf);
  } else if (idx < 19456) {
    int e = idx - 17408; int k = e >> 5, f = e & 31;
    w2t[e] = ldr(g2W, f*64 + k, isf);
  } else if (idx < 35840) {
    int e = idx - 19456;
    wench[e] = (f16)ldr(encWhh, e, isf);
  } else if (idx < 52224) {
    int e = idx - 35840;
    wtah[e] = (f16)ldr(taWhh, e, isf);
  } else if (idx < 117760) {
    int e = idx - 52224;
    wdech[e] = (f16)ldr(decWhh, e, isf);
  }
}

// ---------------- GAT layer 1: ip_emb + dense(32->64) + esed fused ----------------
__global__ __launch_bounds__(256) void gat_dense1_k(const float* __restrict__ x,
    const float* __restrict__ ipW, const float* __restrict__ ipb,
    const float* __restrict__ Wt, const float* __restrict__ as_, const float* __restrict__ ad_,
    bf16* __restrict__ out, float* __restrict__ esed) {
  __shared__ float As[64][33];
  __shared__ float Ws[32][64];
  __shared__ float xs[64][4];
  __shared__ float wipw[128];
  __shared__ float wipb[32];
  const int tid = threadIdx.x;
  const size_t bm = (size_t)blockIdx.x * 64;
  ((float*)xs)[tid] = x[bm*4 + tid];
  if (tid < 128) wipw[tid] = ipW[tid];
  else if (tid < 160) wipb[tid-128] = ipb[tid-128];
  #pragma unroll
  for (int i = 0; i < 8; i++) ((float*)Ws)[tid + 256*i] = Wt[tid + 256*i];
  __syncthreads();
  #pragma unroll
  for (int i = 0; i < 8; i++) {
    int e = tid + 256*i; int v = e >> 5, f = e & 31;
    float a = wipb[f];
    #pragma unroll
    for (int k = 0; k < 4; k++) a += xs[v][k]*wipw[f*4+k];
    As[v][f] = lr01(a);
  }
  __syncthreads();
  const int v = tid >> 2, f0 = (tid & 3) * 16;
  float acc[16];
  #pragma unroll
  for (int i = 0; i < 16; i++) acc[i] = 0.f;
  #pragma unroll 8
  for (int k = 0; k < 32; k++) {
    float a = As[v][k];
    const float4* wr = (const float4*)&Ws[k][f0];
    #pragma unroll
    for (int q = 0; q < 4; q++) {
      float4 w4 = wr[q];
      acc[4*q+0] += a*w4.x; acc[4*q+1] += a*w4.y; acc[4*q+2] += a*w4.z; acc[4*q+3] += a*w4.w;
    }
  }
  bf16* op = out + (bm+v)*64 + f0;
  #pragma unroll
  for (int i = 0; i < 16; i++) op[i] = fbf(acc[i]);
  float es = 0.f, ed = 0.f;
  #pragma unroll
  for (int i = 0; i < 16; i++) { es += acc[i]*as_[f0+i]; ed += acc[i]*ad_[f0+i]; }
  es += __shfl_xor(es, 1); es += __shfl_xor(es, 2);
  ed += __shfl_xor(ed, 1); ed += __shfl_xor(ed, 2);
  if ((tid & 3) == 0) { esed[(bm+v)*2] = es; esed[(bm+v)*2+1] = ed; }
}

// ---------------- GAT layer 2: fused GAT-1 aggregate + dense(64->32) + esed ----------------
// Staging computes the layer-1 aggregate inline from xw1/alph (identical i-order accumulation
// to the old agg8_k<64>, with an explicit bf16 round-trip so As values are bit-identical to
// the old h1 path). Eliminates the h1 HBM round-trip and the agg8<64> dispatch.
__global__ __launch_bounds__(256) void gat_dense2_k(const bf16* __restrict__ xw1,
    const float* __restrict__ alph, const float* __restrict__ bias1,
    const float* __restrict__ Wt, const float* __restrict__ as_, const float* __restrict__ ad_,
    bf16* __restrict__ out, float* __restrict__ esed) {
  __shared__ float As[64][65];
  __shared__ float Ws[64][32];
  const int tid = threadIdx.x;
  const size_t bm = (size_t)blockIdx.x * 64;
  #pragma unroll
  for (int i = 0; i < 8; i++) ((float*)Ws)[tid + 256*i] = Wt[tid + 256*i];
  #pragma unroll
  for (int it = 0; it < 2; it++) {
    const int grp = tid + 256*it;        // 0..511: (node, 8-feat group)
    const int node = grp >> 3;
    const int f0 = (grp & 7) * 8;
    const size_t nid = bm + node;
    const size_t g = nid / 13;
    const int r = (int)(nid - g*13);
    const size_t base = g*13;
    const float* al = alph + g*40;
    float acc[8];
    if (r == 0) {
      #pragma unroll
      for (int j = 0; j < 8; j++) acc[j] = 0.f;
      #pragma unroll
      for (int i = 0; i < 13; i++) {
        const uint4 rv = *(const uint4*)&xw1[(base+i)*64 + f0];
        float a = al[i];
        acc[0] += a*bfu_lo(rv.x); acc[1] += a*bfu_hi(rv.x);
        acc[2] += a*bfu_lo(rv.y); acc[3] += a*bfu_hi(rv.y);
        acc[4] += a*bfu_lo(rv.z); acc[5] += a*bfu_hi(rv.z);
        acc[6] += a*bfu_lo(rv.w); acc[7] += a*bfu_hi(rv.w);
      }
    } else {
      float a0 = al[13 + 2*(r-1)], a1 = al[14 + 2*(r-1)];
      const uint4 r0v = *(const uint4*)&xw1[base*64 + f0];
      const uint4 r1v = *(const uint4*)&xw1[(base+r)*64 + f0];
      acc[0] = a0*bfu_lo(r0v.x) + a1*bfu_lo(r1v.x);
      acc[1] = a0*bfu_hi(r0v.x) + a1*bfu_hi(r1v.x);
      acc[2] = a0*bfu_lo(r0v.y) + a1*bfu_lo(r1v.y);
      acc[3] = a0*bfu_hi(r0v.y) + a1*bfu_hi(r1v.y);
      acc[4] = a0*bfu_lo(r0v.z) + a1*bfu_lo(r1v.z);
      acc[5] = a0*bfu_hi(r0v.z) + a1*bfu_hi(r1v.z);
      acc[6] = a0*bfu_lo(r0v.w) + a1*bfu_lo(r1v.w);
      acc[7] = a0*bfu_hi(r0v.w) + a1*bfu_hi(r1v.w);
    }
    #pragma unroll
    for (int j = 0; j < 8; j++)
      As[node][f0+j] = bff(fbf(lr01(acc[j] + bias1[f0+j])));   // bf16 round-trip = old h1 path
  }
  __syncthreads();
  const int v = tid >> 2, f0 = (tid & 3) * 8;
  float acc[8];
  #pragma unroll
  for (int i = 0; i < 8; i++) acc[i] = 0.f;
  #pragma unroll 8
  for (int k = 0; k < 64; k++) {
    float a = As[v][k];
    const float4* wr = (const float4*)&Ws[k][f0];
    #pragma unroll
    for (int q = 0; q < 2; q++) {
      float4 w4 = wr[q];
      acc[4*q+0] += a*w4.x; acc[4*q+1] += a*w4.y; acc[4*q+2] += a*w4.z; acc[4*q+3] += a*w4.w;
    }
  }
  bf16* op = out + (bm+v)*32 + f0;
  #pragma unroll
  for (int i = 0; i < 8; i++) op[i] = fbf(acc[i]);
  float es = 0.f, ed = 0.f;
  #pragma unroll
  for (int i = 0; i < 8; i++) { es += acc[i]*as_[f0+i]; ed += acc[i]*ad_[f0+i]; }
  es += __shfl_xor(es, 1); es += __shfl_xor(es, 2);
  ed += __shfl_xor(ed, 1); ed += __shfl_xor(ed, 2);
  if ((tid & 3) == 0) { esed[(bm+v)*2] = es; esed[(bm+v)*2+1] = ed; }
}

__global__ __launch_bounds__(256) void alpha_k(const float* __restrict__ esed, float* __restrict__ alph) {
  int g = blockIdx.x*256 + threadIdx.x;                // NGRP
  size_t base = (size_t)g*13;
  float esv[13], edv[13];
  #pragma unroll
  for (int i = 0; i < 13; i++) { esv[i] = esed[(base+i)*2]; edv[i] = esed[(base+i)*2+1]; }
  float* o = alph + (size_t)g*40;
  float e[13]; float m = -1e30f;
  #pragma unroll
  for (int i = 0; i < 13; i++) { float z = lr02(esv[i] + edv[0]); e[i] = z; m = fmaxf(m, z); }
  float den = 0.f;
  #pragma unroll
  for (int i = 0; i < 13; i++) { e[i] = __expf(e[i]-m); den += e[i]; }
  float inv = 1.f/den;
  #pragma unroll
  for (int i = 0; i < 13; i++) o[i] = e[i]*inv;
  #pragma unroll
  for (int j = 1; j <= 12; j++) {
    float z0 = lr02(esv[0] + edv[j]);
    float z1 = lr02(esv[j] + edv[j]);
    float mm = fmaxf(z0, z1);
    float a0 = __expf(z0-mm), a1 = __expf(z1-mm);
    float s = 1.f/(a0+a1);
    o[13 + 2*(j-1)] = a0*s;
    o[14 + 2*(j-1)] = a1*s;
  }
}

// ---------------- GAT aggregate, vectorized 8 f per thread (16B loads) ----------------
template<int F>
__global__ __launch_bounds__(256) void agg8_k(const bf16* __restrict__ xw, const float* __restrict__ alph,
                                              const float* __restrict__ bias, bf16* __restrict__ out) {
  const int NV = F/8;
  size_t idx = (size_t)blockIdx.x*256 + threadIdx.x;   // NNODES * F/8
  int f8 = (int)(idx % NV);
  size_t vn = idx / NV;
  int node = (int)(vn % 13);
  size_t g = vn / 13;
  size_t base = g*13;
  const float* al = alph + g*40;
  const int f0 = f8*8;
  float acc[8];
  if (node == 0) {
    #pragma unroll
    for (int j = 0; j < 8; j++) acc[j] = 0.f;
    #pragma unroll
    for (int i = 0; i < 13; i++) {
      const uint4 rv = *(const uint4*)&xw[(base+i)*F + f0];
      float a = al[i];
      acc[0] += a*bfu_lo(rv.x); acc[1] += a*bfu_hi(rv.x);
      acc[2] += a*bfu_lo(rv.y); acc[3] += a*bfu_hi(rv.y);
      acc[4] += a*bfu_lo(rv.z); acc[5] += a*bfu_hi(rv.z);
      acc[6] += a*bfu_lo(rv.w); acc[7] += a*bfu_hi(rv.w);
    }
  } else {
    float a0 = al[13 + 2*(node-1)], a1 = al[14 + 2*(node-1)];
    const uint4 r0v = *(const uint4*)&xw[base*F + f0];
    const uint4 r1v = *(const uint4*)&xw[(base+node)*F + f0];
    acc[0] = a0*bfu_lo(r0v.x) + a1*bfu_lo(r1v.x);
    acc[1] = a0*bfu_hi(r0v.x) + a1*bfu_hi(r1v.x);
    acc[2] = a0*bfu_lo(r0v.y) + a1*bfu_lo(r1v.y);
    acc[3] = a0*bfu_hi(r0v.y) + a1*bfu_hi(r1v.y);
    acc[4] = a0*bfu_lo(r0v.z) + a1*bfu_lo(r1v.z);
    acc[5] = a0*bfu_hi(r0v.z) + a1*bfu_hi(r1v.z);
    acc[6] = a0*bfu_lo(r0v.w) + a1*bfu_lo(r1v.w);
    acc[7] = a0*bfu_hi(r0v.w) + a1*bfu_hi(r1v.w);
  }
  bf16* op = out + vn*F + f0;
  #pragma unroll
  for (int j = 0; j < 8; j++) op[j] = fbf(lr01(acc[j] + bias[f0+j]));
}

// ---------------- fused embed + MFMA GEMM (ta branch): C[m][n] = x_row(m)@W[n][:], K=144 pad 160 ----------------
template<bool NBR>
__global__ __launch_bounds__(256) void gemm_embed_mfma_k(
    const float* __restrict__ p_in, const float* __restrict__ v_in,
    const float* __restrict__ di_in, const float* __restrict__ l_in,
    const bf16* __restrict__ h2,
    const float* __restrict__ posW, const float* __restrict__ posb,
    const float* __restrict__ vaW, const float* __restrict__ vab,
    const float* __restrict__ disW, const float* __restrict__ disb,
    const float* __restrict__ laneW, const float* __restrict__ laneb,
    const float* __restrict__ W, f16* __restrict__ C, int t0) {
  __shared__ __align__(16) f16 As[128][40];
  __shared__ __align__(16) f16 Bs[128][40];
  const int tid = threadIdx.x;
  const int bm = blockIdx.x * 128, bn = blockIdx.y * 128;
  const int bz = blockIdx.z;
  const int mm = tid & 127, par = tid >> 7;
  int t, n2;
  if (NBR) { t = t0 + bz; n2 = bm + mm; }
  else { int gm = bm + mm; t = gm >> 11; n2 = gm & 2047; }
  const int NROW = NBR ? NBK : NBATCH;
  size_t rn = (size_t)t*NROW + n2;
  const float px0 = p_in[rn*2], px1 = p_in[rn*2+1];
  const float vx0 = v_in[rn*2], vx1 = v_in[rn*2+1];
  const float dx  = di_in[rn];
  const float lx0 = l_in[rn*2], lx1 = l_in[rn*2+1];
  const int b = NBR ? (n2 / KNB) : n2;
  const int node_off = NBR ? (1 + n2 % KNB) : 0;
  const bf16* h2p = h2 + (((size_t)t*NBATCH + b)*13 + node_off)*32;
  const int wn = bn + mm;
  const int l = tid & 63, wv = tid >> 6;
  const int lr = l & 15, lq = l >> 4;
  f32x4 acc[2][8];
  #pragma unroll
  for (int rt = 0; rt < 2; rt++)
    #pragma unroll
    for (int ct = 0; ct < 8; ct++) acc[rt][ct] = (f32x4){0.f,0.f,0.f,0.f};
  for (int ks = 0; ks < 5; ks++) {
    const int k0 = ks*32;
    #pragma unroll
    for (int e = 0; e < 16; e++) {
      int kk = par + 2*e;
      int f = k0 + kk;
      float val;
      if (f < 32) {
        val = lr01(px0*posW[f*2] + px1*posW[f*2+1] + posb[f]);
      } else if (f < 64) {
        int ff = f-32;
        val = lr01(vx0*vaW[ff*2] + vx1*vaW[ff*2+1] + vab[ff]);
      } else if (f < 80) {
        int ff = f-64;
        val = lr01(dx*disW[ff] + disb[ff]);
      } else if (f < 112) {
        int ff = f-80;
        val = lr01(lx0*laneW[ff*2] + lx1*laneW[ff*2+1] + laneb[ff]);
      } else if (f < 144) {
        val = bff(h2p[f-112]);
      } else val = 0.f;
      As[mm][kk] = (f16)val;
      Bs[mm][kk] = (f < 144) ? (f16)W[(size_t)wn*144 + f] : (f16)0.f;
    }
    __syncthreads();
    f16x8 a0 = *(const f16x8*)&As[wv*32 + lr][lq*8];
    f16x8 a1 = *(const f16x8*)&As[wv*32 + 16 + lr][lq*8];
    #pragma unroll
    for (int ct = 0; ct < 8; ct++) {
      f16x8 bfr = *(const f16x8*)&Bs[ct*16 + lr][lq*8];
      acc[0][ct] = MFMA16(a0, bfr, acc[0][ct]);
      acc[1][ct] = MFMA16(a1, bfr, acc[1][ct]);
    }
    __syncthreads();
  }
  #pragma unroll
  for (int rt = 0; rt < 2; rt++)
    #pragma unroll
    for (int ct = 0; ct < 8; ct++)
      #pragma unroll
      for (int rg = 0; rg < 4; rg++) {
        int row = wv*32 + rt*16 + lq*4 + rg;
        int col = ct*16 + lr;
        size_t orow = NBR ? ((size_t)bz*NBK + bm + row) : (size_t)(bm + row);
        C[orow*256 + bn + col] = (f16)acc[rt][ct][rg];
      }
}

// ---------------- combined enc(v8 gate-split) + ta-lstm64 mega kernel ----------------
__global__ __launch_bounds__(512, 4) void enc_ta_mega_k(
    const float* __restrict__ p_in, const float* __restrict__ v_in,
    const float* __restrict__ di_in, const float* __restrict__ l_in,
    const bf16* __restrict__ h2,
    const float* __restrict__ posW, const float* __restrict__ posb,
    const float* __restrict__ vaW, const float* __restrict__ vab,
    const float* __restrict__ disW, const float* __restrict__ disb,
    const float* __restrict__ laneW, const float* __restrict__ laneb,
    const float* __restrict__ Wih, const f16* __restrict__ Whh16,
    const float* __restrict__ bih, const float* __restrict__ bhh,
    float* __restrict__ hstate,
    const f16* __restrict__ XWta, const f16* __restrict__ Whh16ta,
    const float* __restrict__ bihta, const float* __restrict__ bhhta,
    float* __restrict__ h_all_ta) {
  __shared__ __align__(16) union SMem {
    struct { f16 As_s[2][16][168]; f16 h_s[2][16][72]; float gates[16][258]; } e;
    struct { f16 h_s[16][72]; float gates[16][260]; } a;
  } sm;
  const int tid = threadIdx.x;
  const int l = tid & 63;
  const int lr = l & 15, lq = l >> 4;

  if (blockIdx.x < 128) {
    // ================= ta lstm64 path (t0=0, TSEQ steps, nrows=NBATCH) =================
    const int r0 = blockIdx.x * 16;
    const int wv = tid >> 6;           // 0..7; waves 0..3 active
    const int u = l, rg = wv;
    f16x8 bf[4][2];
    if (wv < 4) {
      #pragma unroll
      for (int ct = 0; ct < 4; ct++)
        #pragma unroll
        for (int kt = 0; kt < 2; kt++)
          bf[ct][kt] = *(const f16x8*)&Whh16ta[(size_t)(wv*64 + ct*16 + lr)*64 + kt*32 + lq*8];
    }
    float bj4[4];
    #pragma unroll
    for (int g = 0; g < 4; g++) bj4[g] = bihta[g*64+u] + bhhta[g*64+u];
    for (int i = tid; i < 16*64; i += 512) sm.a.h_s[i>>6][i&63] = (f16)0.f;
    float c[4] = {0.f,0.f,0.f,0.f};
    __syncthreads();
    #pragma unroll 1
    for (int s = 0; s < TSEQ; s++) {
      if (wv < 4) {
        f16x8 a0 = *(const f16x8*)&sm.a.h_s[lr][lq*8];
        f16x8 a1 = *(const f16x8*)&sm.a.h_s[lr][32 + lq*8];
        f32x4 acc[4];
        #pragma unroll
        for (int ct = 0; ct < 4; ct++) {
          acc[ct] = (f32x4){0.f,0.f,0.f,0.f};
          acc[ct] = MFMA16(a0, bf[ct][0], acc[ct]);
          acc[ct] = MFMA16(a1, bf[ct][1], acc[ct]);
        }
        #pragma unroll
        for (int ct = 0; ct < 4; ct++)
          #pragma unroll
          for (int q2 = 0; q2 < 4; q2++)
            sm.a.gates[lq*4 + q2][wv*64 + ct*16 + lr] = acc[ct][q2];
      }
      __syncthreads();
      if (wv < 4) {
        const f16* xwrow = XWta + ((size_t)s*NBATCH + r0)*256;
        #pragma unroll
        for (int q = 0; q < 4; q++) {
          const int r = rg*4 + q;
          float gi = sm.a.gates[r][u]     + bj4[0] + (float)xwrow[(size_t)r*256 + u];
          float gf = sm.a.gates[r][64+u]  + bj4[1] + (float)xwrow[(size_t)r*256 + 64 + u];
          float gg = sm.a.gates[r][128+u] + bj4[2] + (float)xwrow[(size_t)r*256 + 128 + u];
          float go = sm.a.gates[r][192+u] + bj4[3] + (float)xwrow[(size_t)r*256 + 192 + u];
          float cv = sigm(gf)*c[q] + sigm(gi)*tanhe(gg);
          c[q] = cv;
          float hv = sigm(go)*tanhe(cv);
          sm.a.h_s[r][u] = (f16)hv;
          h_all_ta[((size_t)s*NBATCH + r0 + r)*64 + u] = hv;
        }
      }
      __syncthreads();
    }
    return;
  }

  // ================= enc path =================
  const int r0 = (blockIdx.x - 128) * 16;
  const int w = tid >> 6;              // 8 waves
  const int cu0 = w*16 + lr;
  const int cu1 = 128 + cu0;
  f16x8 bxw[2][5];
  f16x8 bhw[2][2];
  float bv[2];
  #pragma unroll
  for (int s = 0; s < 2; s++) {
    const int cu = s ? cu1 : cu0;
    const float* wr = Wih + (size_t)cu*144;
    #pragma unroll
    for (int ks = 0; ks < 5; ks++) {
      f16x8 v;
      #pragma unroll
      for (int j = 0; j < 8; j++) {
        int k = ks*32 + lq*8 + j;
        v[j] = (k < 144) ? (f16)wr[k] : (f16)0.f;
      }
      bxw[s][ks] = v;
    }
    #pragma unroll
    for (int kt = 0; kt < 2; kt++)
      bhw[s][kt] = *(const f16x8*)&Whh16[(size_t)cu*64 + kt*32 + lq*8];
    bv[s] = bih[cu] + bhh[cu];
  }
  const int prow = tid & 15;
  const int pq = tid >> 4;
  const int n2 = r0 + prow;
  const int bb = n2 / KNB;
  const int noff = 1 + n2 - bb*KNB;
  float c0 = 0.f, c1 = 0.f;
  float La = 0.f, Lb = 0.f;
  uint4 HA = {0,0,0,0};
  for (int i = tid; i < 16*64; i += 512) sm.e.h_s[0][i>>6][i&63] = (f16)0.f;

#define ENC_ISSUE(TP) do {                                                   \
    const size_t rnp = (size_t)(TP)*NBK + n2;                                \
    if (pq < 4)       { float2 p = *(const float2*)(p_in + rnp*2); La = p.x; Lb = p.y; } \
    else if (pq < 8)  { float2 p = *(const float2*)(v_in + rnp*2); La = p.x; Lb = p.y; } \
    else if (pq < 10) { La = di_in[rnp]; }                                   \
    else if (pq < 14) { float2 p = *(const float2*)(l_in + rnp*2); La = p.x; Lb = p.y; } \
    else if (pq < 18) { HA = *(const uint4*)(h2 + (((size_t)(TP)*NBATCH + bb)*13 + noff)*32 + (pq-14)*8); } \
  } while (0)

#define ENC_STAGE(BUF) do {                                                  \
    if (pq < 20) {                                                           \
      const int f0 = pq*8;                                                   \
      f16x8 v;                                                               \
      if (f0 < 32) {                                                         \
        _Pragma("unroll")                                                    \
        for (int j = 0; j < 8; j++)                                          \
          v[j] = (f16)lr01(La*posW[(f0+j)*2] + Lb*posW[(f0+j)*2+1] + posb[f0+j]); \
      } else if (f0 < 64) {                                                  \
        _Pragma("unroll")                                                    \
        for (int j = 0; j < 8; j++) {                                        \
          int ff = f0+j-32;                                                  \
          v[j] = (f16)lr01(La*vaW[ff*2] + Lb*vaW[ff*2+1] + vab[ff]);         \
        }                                                                    \
      } else if (f0 < 80) {                                                  \
        _Pragma("unroll")                                                    \
        for (int j = 0; j < 8; j++) {                                        \
          int ff = f0+j-64;                                                  \
          v[j] = (f16)lr01(La*disW[ff] + disb[ff]);                          \
        }                                                                    \
      } else if (f0 < 112) {                                                 \
        _Pragma("unroll")                                                    \
        for (int j = 0; j < 8; j++) {                                        \
          int ff = f0+j-80;                                                  \
          v[j] = (f16)lr01(La*laneW[ff*2] + Lb*laneW[ff*2+1] + laneb[ff]);   \
        }                                                                    \
      } else if (f0 < 144) {                                                 \
        v[0] = (f16)bfu_lo(HA.x); v[1] = (f16)bfu_hi(HA.x);                  \
        v[2] = (f16)bfu_lo(HA.y); v[3] = (f16)bfu_hi(HA.y);                  \
        v[4] = (f16)bfu_lo(HA.z); v[5] = (f16)bfu_hi(HA.z);                  \
        v[6] = (f16)bfu_lo(HA.w); v[7] = (f16)bfu_hi(HA.w);                  \
      } else {                                                               \
        _Pragma("unroll")                                                    \
        for (int j = 0; j < 8; j++) v[j] = (f16)0.f;                         \
      }                                                                      \
      *(f16x8*)&sm.e.As_s[BUF][prow][f0] = v;                                \
    }                                                                        \
  } while (0)

  ENC_ISSUE(0);
  ENC_STAGE(0);
  __syncthreads();
  int cur = 0;
  #pragma unroll 1
  for (int t = 0; t < TSEQ; t++) {
    const int tp = (t+1 < TSEQ) ? t+1 : t;
    ENC_ISSUE(tp);
    {
      f16x8 ae0 = *(const f16x8*)&sm.e.As_s[cur][lr][lq*8];
      f16x8 ae1 = *(const f16x8*)&sm.e.As_s[cur][lr][32 + lq*8];
      f16x8 ae2 = *(const f16x8*)&sm.e.As_s[cur][lr][64 + lq*8];
      f16x8 ae3 = *(const f16x8*)&sm.e.As_s[cur][lr][96 + lq*8];
      f16x8 ae4 = *(const f16x8*)&sm.e.As_s[cur][lr][128 + lq*8];
      f16x8 ah0 = *(const f16x8*)&sm.e.h_s[cur][lr][lq*8];
      f16x8 ah1 = *(const f16x8*)&sm.e.h_s[cur][lr][32 + lq*8];
      #pragma unroll
      for (int s = 0; s < 2; s++) {
        f32x4 a = (f32x4){0.f,0.f,0.f,0.f};
        a = MFMA16(ae0, bxw[s][0], a);
        a = MFMA16(ae1, bxw[s][1], a);
        a = MFMA16(ae2, bxw[s][2], a);
        a = MFMA16(ae3, bxw[s][3], a);
        a = MFMA16(ae4, bxw[s][4], a);
        a = MFMA16(ah0, bhw[s][0], a);
        a = MFMA16(ah1, bhw[s][1], a);
        const int cu = s ? cu1 : cu0;
        #pragma unroll
        for (int q = 0; q < 4; q++)
          sm.e.gates[lq*4 + q][cu] = a[q] + bv[s];
      }
    }
    __syncthreads();
    {
      const int u0 = pq*2;
      const float* gr = &sm.e.gates[prow][0];
      float gi0 = gr[u0],       gi1 = gr[u0+1];
      float gf0 = gr[64+u0],    gf1 = gr[64+u0+1];
      float gg0 = gr[128+u0],   gg1 = gr[128+u0+1];
      float go0 = gr[192+u0],   go1 = gr[192+u0+1];
      float cv0 = sigm(gf0)*c0 + sigm(gi0)*tanhe(gg0);
      float cv1 = sigm(gf1)*c1 + sigm(gi1)*tanhe(gg1);
      c0 = cv0; c1 = cv1;
      f16x2 hv;
      hv[0] = (f16)(sigm(go0)*tanhe(cv0));
      hv[1] = (f16)(sigm(go1)*tanhe(cv1));
      *(f16x2*)&sm.e.h_s[cur^1][prow][u0] = hv;
    }
    ENC_STAGE(cur^1);
    __syncthreads();
    cur ^= 1;
  }
#undef ENC_ISSUE
#undef ENC_STAGE
  for (int i = tid; i < 16*64; i += 512)
    hstate[(size_t)(r0 + (i>>6))*64 + (i&63)] = (float)sm.e.h_s[cur][i>>6][i&63];
}

// ---------------- merged heads: gemm_bt (blocks 0..63) + latlon (blocks 64..71) ----------------
__global__ __launch_bounds__(256, 2) void head_k(const bf16* __restrict__ A, const float* __restrict__ W,
    float* __restrict__ C, int N, int Kd,
    const float* __restrict__ e192,
    const float* __restrict__ latW, const float* __restrict__ latb,
    const float* __restrict__ lonW, const float* __restrict__ lonb,
    void* __restrict__ out, const int* __restrict__ flag) {
  const int tid = threadIdx.x;
  if (blockIdx.x < 64) {
    __shared__ __align__(16) float As[8][132];
    __shared__ __align__(16) float Bs[8][132];
    const int bm = (blockIdx.x >> 2) * 128, bn = (blockIdx.x & 3) * 128;
    const int tx = tid & 15, ty = tid >> 4;
    float acc[8][8];
    #pragma unroll
    for (int i = 0; i < 8; i++)
      #pragma unroll
      for (int j = 0; j < 8; j++) acc[i][j] = 0.f;
    for (int k0 = 0; k0 < Kd; k0 += 8) {
      #pragma unroll
      for (int i = 0; i < 4; i++) {
        int lin = tid + 256*i;
        int kk = lin & 7, mm = lin >> 3;
        int gk = k0 + kk;
        As[kk][mm] = (gk < Kd) ? bff(A[(size_t)(bm+mm)*Kd + gk]) : 0.f;
        Bs[kk][mm] = (gk < Kd) ? W[(size_t)(bn+mm)*Kd + gk] : 0.f;
      }
      __syncthreads();
      #pragma unroll
      for (int kk = 0; kk < 8; kk++) {
        float4 a0 = *(const float4*)&As[kk][ty*4];
        float4 a1 = *(const float4*)&As[kk][64+ty*4];
        float4 b0 = *(const float4*)&Bs[kk][tx*4];
        float4 b1 = *(const float4*)&Bs[kk][64+tx*4];
        float av[8] = {a0.x,a0.y,a0.z,a0.w,a1.x,a1.y,a1.z,a1.w};
        float bvv[8] = {b0.x,b0.y,b0.z,b0.w,b1.x,b1.y,b1.z,b1.w};
        #pragma unroll
        for (int i = 0; i < 8; i++)
          #pragma unroll
          for (int j = 0; j < 8; j++) acc[i][j] += av[i]*bvv[j];
      }
      __syncthreads();
    }
    #pragma unroll
    for (int i = 0; i < 8; i++) {
      int m = bm + (i>>2)*64 + ty*4 + (i&3);
      #pragma unroll
      for (int jh = 0; jh < 2; jh++) {
        float4 v = make_float4(acc[i][jh*4+0], acc[i][jh*4+1], acc[i][jh*4+2], acc[i][jh*4+3]);
        *(float4*)&C[(size_t)m*N + bn + jh*64 + tx*4] = v;
      }
    }
  } else {
    int b = (blockIdx.x - 64)*256 + tid;               // NBATCH
    const int isf = *flag;
    const float* e = e192 + (size_t)b*192;
    float s[3];
    #pragma unroll
    for (int c2 = 0; c2 < 3; c2++) {
      float acc = latb[c2];
      for (int k = 0; k < 192; k++) acc += e[k]*latW[c2*192+k];
      s[c2] = acc;
    }
    float m = fmaxf(s[0], fmaxf(s[1], s[2]));
    float e0 = __expf(s[0]-m), e1 = __expf(s[1]-m), e2 = __expf(s[2]-m);
    float inv = 1.f/(e0+e1+e2);
    stout(out, isf, 256000 + (size_t)b*3 + 0, e0*inv);
    stout(out, isf, 256000 + (size_t)b*3 + 1, e1*inv);
    stout(out, isf, 256000 + (size_t)b*3 + 2, e2*inv);
    float q[2];
    #pragma unroll
    for (int c2 = 0; c2 < 2; c2++) {
      float acc = lonb[c2];
      for (int k = 0; k < 192; k++) acc += e[k]*lonW[c2*192+k];
      q[c2] = acc;
    }
    float m2 = fmaxf(q[0], q[1]);
    float f0 = __expf(q[0]-m2), f1 = __expf(q[1]-m2);
    float inv2 = 1.f/(f0+f1);
    stout(out, isf, 262144 + (size_t)b*2 + 0, f0*inv2);
    stout(out, isf, 262144 + (size_t)b*2 + 1, f1*inv2);
  }
}

// ---------------- MFMA LSTM H=128 (dec) + fused output projection ----------------
__global__ __launch_bounds__(512) void lstm128_out_k(const float* __restrict__ XW,
    const f16* __restrict__ Whh16, const float* __restrict__ bih, const float* __restrict__ bhh,
    int steps, const float* __restrict__ opW, const float* __restrict__ opb,
    void* __restrict__ out, const int* __restrict__ flag) {
  __shared__ __align__(16) f16 h_s[2][16][136];
  __shared__ float hsf[2][16][132];
  __shared__ float opWs[640];
  __shared__ float opbs[5];
  const int tid = threadIdx.x;
  const int r0 = blockIdx.x * 16;
  const int l = tid & 63, wv = tid >> 6;
  const int lr = l & 15, lq = l >> 4;
  const int u = wv*16 + lr;
  const int isf = *flag;
  f16x8 bf[4][4];
  #pragma unroll
  for (int g = 0; g < 4; g++)
    #pragma unroll
    for (int kt = 0; kt < 4; kt++)
      bf[g][kt] = *(const f16x8*)&Whh16[(size_t)(g*128 + u)*128 + kt*32 + lq*8];
  float xr[4][4];
  #pragma unroll
  for (int g = 0; g < 4; g++) {
    float bj = bih[g*128 + u] + bhh[g*128 + u];
    #pragma unroll
    for (int rg = 0; rg < 4; rg++)
      xr[g][rg] = XW[(size_t)(r0 + lq*4 + rg)*512 + g*128 + u] + bj;
  }
  for (int i = tid; i < 16*128; i += 512) h_s[0][i>>7][i&127] = (f16)0.f;
  for (int i = tid; i < 640; i += 512) opWs[i] = opW[i];
  if (tid < 5) opbs[tid] = opb[tid];
  float c[4] = {0.f,0.f,0.f,0.f};
  __syncthreads();
  int cur = 0;
  #pragma unroll 1
  for (int t = 0; t < steps; t++) {
    f16x8 a0 = *(const f16x8*)&h_s[cur][lr][lq*8];
    f16x8 a1 = *(const f16x8*)&h_s[cur][lr][32 + lq*8];
    f16x8 a2 = *(const f16x8*)&h_s[cur][lr][64 + lq*8];
    f16x8 a3 = *(const f16x8*)&h_s[cur][lr][96 + lq*8];
    f32x4 acc[4];
    #pragma unroll
    for (int g = 0; g < 4; g++) {
      acc[g] = (f32x4){0.f,0.f,0.f,0.f};
      acc[g] = MFMA16(a0, bf[g][0], acc[g]);
      acc[g] = MFMA16(a1, bf[g][1], acc[g]);
      acc[g] = MFMA16(a2, bf[g][2], acc[g]);
      acc[g] = MFMA16(a3, bf[g][3], acc[g]);
    }
    #pragma unroll
    for (int rg = 0; rg < 4; rg++) {
      const int row = lq*4 + rg;
      float gi = acc[0][rg] + xr[0][rg];
      float gf = acc[1][rg] + xr[1][rg];
      float gg = acc[2][rg] + xr[2][rg];
      float go = acc[3][rg] + xr[3][rg];
      float cv = sigm(gf)*c[rg] + sigm(gi)*tanhe(gg);
      c[rg] = cv;
      float hv = sigm(go)*tanhe(cv);
      h_s[cur^1][row][u] = (f16)hv;
      hsf[cur^1][row][u] = hv;
    }
    __syncthreads();
    if (tid < 80) {
      const int row = tid / 5, c2 = tid - (tid/5)*5;
      float acc2 = opbs[c2];
      const float* hr = &hsf[cur^1][row][0];
      for (int k = 0; k < 128; k++) acc2 += hr[k]*opWs[c2*128+k];
      size_t oidx = ((size_t)t*NBATCH + r0 + row)*5 + c2;
      float v = (c2 < 2) ? acc2 : (c2 < 4 ? __expf(acc2) : tanhe(acc2));
      stout(out, isf, oidx, v);
    }
    cur ^= 1;
  }
}

// ---------------- fused temporal attention: scores + softmax + context ----------------
__global__ __launch_bounds__(256) void ta_fused_k(const float* __restrict__ hs,
    const float* __restrict__ W, const float* __restrict__ bias,
    const float* __restrict__ dynW, const float* __restrict__ dynb,
    float* __restrict__ henc) {
  __shared__ float hsl[8][1024];
  __shared__ float scl[8][16];
  const int tid = threadIdx.x;
  const int b0 = blockIdx.x * 8;
  for (int i = tid; i < 8*1024; i += 256) {
    int bb = i >> 10, r = i & 1023;
    int t = r >> 6, h = r & 63;
    hsl[bb][r] = hs[((size_t)t*NBATCH + b0 + bb)*64 + h];
  }
  __syncthreads();
  if (tid < 128) {
    int bb = tid >> 4, i = tid & 15;
    float acc = bias[i];
    for (int t = 0; t < 16; t++) {
      const float* hr = &hsl[bb][t*64];
      const float* wr = W + (size_t)i*1024 + t*64;
      #pragma unroll
      for (int h = 0; h < 64; h++) acc += hr[h]*wr[h];
    }
    scl[bb][i] = fmaxf(acc, 0.f);
  }
  __syncthreads();
  {
    int bb = tid >> 5, o = tid & 31;
    const float* s = scl[bb];
    float m = s[0];
    #pragma unroll
    for (int t = 1; t < 16; t++) m = fmaxf(m, s[t]);
    float e[16]; float den = 0.f;
    #pragma unroll
    for (int t = 0; t < 16; t++) { e[t] = __expf(s[t]-m); den += e[t]; }
    float inv = 1.f/den;
    float acc = dynb[o];
    for (int t = 0; t < 16; t++) {
      const float* hr = &hsl[bb][t*64];
      float inner = 0.f;
      #pragma unroll
      for (int h = 0; h < 64; h++) inner += hr[h]*dynW[(size_t)o*64 + h];
      acc += (e[t]*inv)*inner;
    }
    henc[(size_t)(b0+bb)*32 + o] = lr01(acc);
  }
}

// ---------------- fused social conv: conv1 -> conv2 -> pool -> e192/encd ----------------
__global__ __launch_bounds__(256) void fused_conv_k(const float* __restrict__ nenc,
    const f16* __restrict__ wp1t, const f16* __restrict__ wp2t,
    const float* __restrict__ scb, const float* __restrict__ c31b,
    const float* __restrict__ henc, const float* __restrict__ lat_enc, const float* __restrict__ lon_enc,
    float* __restrict__ e192, bf16* __restrict__ encd) {
  __shared__ f16 ws1[12288];
  __shared__ f16 ws2[3072];
  __shared__ float img[4][13][64];
  __shared__ float c1s[4][64][12];
  __shared__ float c2s[4][16][9];
  const int tid = threadIdx.x;
  const int l = tid & 63, wv = tid >> 6;
  const int b = blockIdx.x*4 + wv;
  #pragma unroll
  for (int it = 0; it < 24; it++) ((uint32_t*)ws1)[tid + 256*it] = ((const uint32_t*)wp1t)[tid + 256*it];
  #pragma unroll
  for (int it = 0; it < 6; it++) ((uint32_t*)ws2)[tid + 256*it] = ((const uint32_t*)wp2t)[tid + 256*it];
  #pragma unroll
  for (int it = 0; it < 13; it++)
    img[wv][it][l] = (it < 12) ? nenc[((size_t)b*12 + it)*64 + l] : 0.f;
  __syncthreads();
  {
    const int o = l;
    float acc[11];
    float bv = scb[o];
    #pragma unroll
    for (int h = 0; h < 11; h++) acc[h] = bv;
    for (int k = 0; k < 192; k++) {
      int kh = k >> 6, i = k & 63;
      float w = (float)ws1[k*64 + o];
      const float* ic = img[wv][kh];
      #pragma unroll
      for (int h = 0; h < 11; h++) acc[h] += ic[h*64 + i] * w;
    }
    #pragma unroll
    for (int h = 0; h < 11; h++) c1s[wv][o][h] = lr01(acc[h]);
  }
  __syncthreads();
  if (l < 48) {
    const int o2 = l / 3, jg = l - o2*3;
    float acc[3];
    float bv = c31b[o2];
    #pragma unroll
    for (int m = 0; m < 3; m++) acc[m] = bv;
    for (int k = 0; k < 192; k++) {
      int kh = k >> 6, i = k & 63;
      float w = (float)ws2[k*16 + o2];
      #pragma unroll
      for (int m = 0; m < 3; m++) acc[m] += c1s[wv][i][jg*3 + m + kh] * w;
    }
    #pragma unroll
    for (int m = 0; m < 3; m++) c2s[wv][o2][jg*3 + m] = lr01(acc[m]);
  }
  __syncthreads();
  for (int it = 0; it < 4; it++) {
    int k = l + it*64;
    if (k >= 197) break;
    float val;
    if (k < 192) {
      if (k < 160) {
        bool is_av = (k >= 80);
        int rel = is_av ? (k - 80) : k;
        int o = rel / 5, p = rel - o*5;
        const float* r = c2s[wv][o];
        float v2 = r[2*p];
        if (p == 0) val = is_av ? v2*0.5f : v2;
        else { float v1 = r[2*p-1]; val = is_av ? (v1+v2)*0.5f : fmaxf(v1, v2); }
      } else {
        val = henc[(size_t)b*32 + (k-160)];
      }
      e192[(size_t)b*192 + k] = val;
    } else if (k < 195) {
      val = lat_enc[(size_t)b*3 + (k-192)];
    } else {
      val = lon_enc[(size_t)b*2 + (k-195)];
    }
    encd[(size_t)b*197 + k] = fbf(val);
  }
}

// ---------------- workspace layout (f32-slot offsets) ----------------
static const size_t OFF_H2   = 0;
static const size_t OFF_P    = 6815744;     // xw2 (GAT-2 output; old h1 slot)
static const size_t OFF_Q    = 20447232;    // xw1 (GAT-1 output)
static const size_t OFF_ESED = 34078720;
static const size_t OFF_ALPH = 34930688;    // -> end 36,241,408
static const size_t OFF_XWTA = 6815744;     // f16 (ta phase; reuses OFF_P after xw2 consumed)
static const size_t OFF_HSTA = 15204352;    // ta phase
static const size_t OFF_HST  = 23691264;
static const size_t OFF_E192 = 28573696;
static const size_t OFF_ENCD = 28966912;
static const size_t OFF_XWD  = 29168640;
static const size_t OFF_HEN  = 35000000;
static const size_t OFF_CVT  = 36241408;
static const size_t OFF_WP1T = 41280000;
static const size_t OFF_WP2T = 41286144;
static const size_t OFF_W1T  = 41287680;
static const size_t OFF_W2T  = 41289728;
static const size_t OFF_WENC = 41291776;    // f16 x 16384
static const size_t OFF_WTAH = 41299968;    // f16 x 16384
static const size_t OFF_WDECH= 41308160;    // f16 x 65536 (32768 slots)
static const size_t OFF_FLAG = 41400000;

extern "C" void kernel_launch(void* const* d_in, const int* in_sizes, int n_in,
                              void* d_out, int out_size, void* d_ws, size_t ws_size,
                              hipStream_t stream) {
  (void)in_sizes; (void)n_in; (void)out_size; (void)ws_size;
  float* ws = (float*)d_ws;
  int* flag = (int*)(ws + OFF_FLAG);

  static const int   cidx[NCVT] = {0,3,4,5,6,7,8,9,10,12,13,
    14,15,16,17,18,19,20,21,22,23,24,25,26,27,28,29,30,31,
    32,33,34,35,36,37,38,39,40,41,42,43,44,45,46,47,
    48,49,50,51,52,53,54,55,56,57};
  static const unsigned ccnt[NCVT] = {1703936,65536,65536,32768,65536,786432,786432,393216,786432,6144,4096,
    128,32,2048,64,64,64,2048,32,32,32,64,32,64,32,16,16,64,32,
    36864,16384,256,256,36864,16384,256,256,16384,16,2048,32,36864,64,3072,16,
    100864,65536,512,512,640,5,576,3,384,2};
  CvtArgs ca;
  unsigned total = 0;
  float* cp[58];
  for (int i = 0; i < NCVT; i++) {
    ca.src[i] = d_in[cidx[i]];
    ca.off[i] = total;
    ca.cnt[i] = ccnt[i];
    cp[cidx[i]] = ws + OFF_CVT + total;
    total += ccnt[i];
  }
  detect_k<<<1,256,0,stream>>>((const uint32_t*)d_in[0], flag);

  void* out = d_out;
  bf16*  h2    = (bf16*)(ws + OFF_H2);
  bf16*  xw1   = (bf16*)(ws + OFF_Q);
  bf16*  xw2   = (bf16*)(ws + OFF_P);
  float* esed  = ws + OFF_ESED;
  float* alph  = ws + OFF_ALPH;
  f16*   xwta  = (f16*)(ws + OFF_XWTA);
  float* hsta  = ws + OFF_HSTA;
  float* henc  = ws + OFF_HEN;
  float* hst   = ws + OFF_HST;
  float* e192  = ws + OFF_E192;
  bf16*  encd  = (bf16*)(ws + OFF_ENCD);
  float* xwd   = ws + OFF_XWD;
  f16*   wp1t  = (f16*)(ws + OFF_WP1T);
  f16*   wp2t  = (f16*)(ws + OFF_WP2T);
  float* w1t   = ws + OFF_W1T;
  float* w2t   = ws + OFF_W2T;
  f16*   wench = (f16*)(ws + OFF_WENC);
  f16*   wtah  = (f16*)(ws + OFF_WTAH);
  f16*   wdech = (f16*)(ws + OFF_WDECH);

  // ---- convert + weight repack in one kernel ----
  cvtprep_k<<<4556,256,0,stream>>>(ca, ws + OFF_CVT, flag, total,
      d_in[44], d_in[46], d_in[16], d_in[20], d_in[33], d_in[37], d_in[49],
      wp1t, wp2t, w1t, w2t, wench, wtah, wdech);

  // ---- GAT (dense1+esed -> alpha -> fused agg+dense2+esed -> alpha -> agg) ----
  gat_dense1_k<<<6656,256,0,stream>>>(cp[0], cp[14], cp[15], w1t, cp[17], cp[18], xw1, esed);
  alpha_k<<<128,256,0,stream>>>(esed, alph);
  gat_dense2_k<<<6656,256,0,stream>>>(xw1, alph, cp[19], w2t, cp[21], cp[22], xw2, esed);
  alpha_k<<<128,256,0,stream>>>(esed, alph);
  agg8_k<32><<<6656,256,0,stream>>>(xw2, alph, cp[23], h2);

  // ---- ta-branch x-projection ----
  gemm_embed_mfma_k<false><<<dim3(256,2,1),256,0,stream>>>(cp[3], cp[4], cp[5], cp[6], h2,
      cp[24],cp[25],cp[26],cp[27],cp[28],cp[29],cp[30],cp[31], cp[36], xwta, 0);

  // ---- combined: ta lstm64 (128 blocks) + enc gate-split LSTM (1536 blocks) ----
  enc_ta_mega_k<<<1664,512,0,stream>>>(cp[7], cp[8], cp[9], cp[10], h2,
      cp[24],cp[25],cp[26],cp[27],cp[28],cp[29],cp[30],cp[31],
      cp[32], wench, cp[34], cp[35], hst,
      xwta, wtah, cp[38], cp[39], hsta);

  // ---- fused temporal attention (scores + softmax + ctx) ----
  ta_fused_k<<<256,256,0,stream>>>(hsta, cp[40], cp[41], cp[42], cp[43], henc);

  // ---- fused social conv + pool + enc build ----
  fused_conv_k<<<512,256,0,stream>>>(hst, wp1t, wp2t, cp[45], cp[47], henc, cp[12], cp[13], e192, encd);

  // ---- merged heads: dec projection GEMM + lat/lon softmax ----
  head_k<<<72,256,0,stream>>>(encd, cp[48], xwd, 512, 197,
      e192, cp[54], cp[55], cp[56], cp[57], out, flag);

  // ---- dec LSTM with fused output projection ----
  lstm128_out_k<<<128,512,0,stream>>>(xwd, wdech, cp[50], cp[51], NTOUT,
      cp[52], cp[53], out, flag);
}